// Round 12
// baseline (710.386 us; speedup 1.0000x reference)
//
#include <hip/hip_runtime.h>
#include <hip/hip_bf16.h>
#include <cstdint>

typedef unsigned short u16;
typedef unsigned int u32;
typedef __attribute__((ext_vector_type(4))) float floatx4;
typedef __attribute__((ext_vector_type(8))) short shortx8;

#define G_STEP 8192
#define N_TOTAL 131072
#define RHALF (1280*256)

__device__ __forceinline__ float bfu2f(u16 x){ return __uint_as_float(((unsigned)x)<<16); }
__device__ __forceinline__ u16 f2bfu(float x){ __hip_bfloat16 b = __float2bfloat16(x); return *reinterpret_cast<u16*>(&b); }
__device__ __forceinline__ float sigm(float x){ return 1.0f/(1.0f+__expf(-x)); }
__device__ __forceinline__ float tanh_(float x){
  float cx = fminf(fmaxf(x,-15.f),15.f);
  float e = __expf(2.f*cx);
  return (e-1.f)/(e+1.f);
}
__device__ __forceinline__ float invs(float x){ return 1.0f/sqrtf(x); }

__device__ __forceinline__ void gl16(const void* g, void* l){
  __builtin_amdgcn_global_load_lds((const __attribute__((address_space(1))) u32*)g,
                                   (__attribute__((address_space(3))) u32*)l, 16, 0, 0);
}

__device__ __forceinline__ void cvt8(const float* __restrict__ src, u16* __restrict__ dst){
  float4 a = *reinterpret_cast<const float4*>(src);
  float4 b = *reinterpret_cast<const float4*>(src+4);
  ushort4 o0; o0.x=f2bfu(a.x); o0.y=f2bfu(a.y); o0.z=f2bfu(a.z); o0.w=f2bfu(a.w);
  ushort4 o1; o1.x=f2bfu(b.x); o1.y=f2bfu(b.y); o1.z=f2bfu(b.z); o1.w=f2bfu(b.w);
  *reinterpret_cast<ushort4*>(dst)   = o0;
  *reinterpret_cast<ushort4*>(dst+4) = o1;
}

// ---------------------------------------------------------------- setup (fused prep + leaf + num_pre + sumsq init)
__global__ __launch_bounds__(256) void setup_kernel(
    const int* __restrict__ tokens, const float* __restrict__ leaf_table,
    const float* __restrict__ W1, const float* __restrict__ b1,
    const float* __restrict__ una_W, const float* __restrict__ bin_W,
    const float* __restrict__ num_W2,
    u16* __restrict__ wbu, u16* __restrict__ wbb, u16* __restrict__ wbn,
    u16* __restrict__ h1, u16* __restrict__ H, u16* __restrict__ C,
    float* __restrict__ sumsq)
{
  const int b = blockIdx.x, tid = threadIdx.x;
  if (b < 256){                                  // wbu: 2048 rows
    int row = b*8 + (tid>>5), d0 = (tid&31)*8;
    int op = row>>10, w = row&1023;
    int gate = (w>>4)&3, e = ((w>>6)<<4) | (w&15);
    cvt8(una_W + (size_t)((op*4+gate)*256 + e)*256 + d0, wbu + (size_t)row*256 + d0);
  } else if (b < 896){                           // wbb: 5120 rows
    int row = (b-256)*8 + (tid>>5), d0 = (tid&31)*8;
    int ob = row / 2560, rem = row - ob*2560;
    int lr = rem / 1280, rw = rem - lr*1280;
    int eblk = rw / 80, rem2 = rw - eblk*80;
    int gate = rem2 >> 4, el = rem2 & 15;
    int e = eblk*16 + el;
    cvt8(bin_W + (size_t)((ob*10 + 2*gate + lr)*256 + e)*256 + d0, wbb + (size_t)row*256 + d0);
  } else if (b < 928){                           // wbn: 256 rows plain
    int row = (b-896)*8 + (tid>>5), d0 = (tid&31)*8;
    cvt8(num_W2 + (size_t)row*256 + d0, wbn + (size_t)row*256 + d0);
  } else if (b < 2976){                          // leaf: 8192 nodes, 4/block
    int wave = tid >> 6, lane = tid & 63;
    int node = (b-928)*4 + wave;
    int t = tokens[node];
    const float4 e4 = *reinterpret_cast<const float4*>(leaf_table + (size_t)t*256 + lane*4);
    float ss = e4.x*e4.x + e4.y*e4.y + e4.z*e4.z + e4.w*e4.w;
    #pragma unroll
    for (int o = 32; o; o >>= 1) ss += __shfl_down(ss, o);
    ss = __shfl(ss, 0);
    float scale = fminf(1.0f, 1.0f/(sqrtf(ss) + 1e-7f));
    ushort4 hv;
    hv.x = f2bfu(e4.x*scale); hv.y = f2bfu(e4.y*scale);
    hv.z = f2bfu(e4.z*scale); hv.w = f2bfu(e4.w*scale);
    ushort4 zv; zv.x = zv.y = zv.z = zv.w = 0;
    *reinterpret_cast<ushort4*>(H + (size_t)node*256 + lane*4) = hv;
    *reinterpret_cast<ushort4*>(C + (size_t)node*256 + lane*4) = zv;
  } else if (b < 4000){                          // num_pre: 2M elems, 8/thread
    int flat = (b-2976)*2048 + tid*8;
    int n = flat >> 8, d0 = flat & 255;
    float x = (float)tokens[G_STEP + n];
    float4 w0 = *reinterpret_cast<const float4*>(W1 + d0);
    float4 w1 = *reinterpret_cast<const float4*>(W1 + d0 + 4);
    float4 c0 = *reinterpret_cast<const float4*>(b1 + d0);
    float4 c1 = *reinterpret_cast<const float4*>(b1 + d0 + 4);
    ushort4 o0, o1;
    o0.x = f2bfu(sigm(x*w0.x + c0.x)); o0.y = f2bfu(sigm(x*w0.y + c0.y));
    o0.z = f2bfu(sigm(x*w0.z + c0.z)); o0.w = f2bfu(sigm(x*w0.w + c0.w));
    o1.x = f2bfu(sigm(x*w1.x + c1.x)); o1.y = f2bfu(sigm(x*w1.y + c1.y));
    o1.z = f2bfu(sigm(x*w1.z + c1.z)); o1.w = f2bfu(sigm(x*w1.w + c1.w));
    *reinterpret_cast<ushort4*>(h1 + flat)     = o0;
    *reinterpret_cast<ushort4*>(h1 + flat + 4) = o1;
  } else {                                       // sumsq init
    if (tid < 32) sumsq[tid] = ((tid & 15) < 2) ? 1.0f : 0.0f;
  }
}

// ---------------------------------------------------------------- fused GEMM + LSTM cell, deferred H-norm
// A-DIRECT build: A fragments load straight global->VGPR per lane (no LDS, no
// staging sync; compiler-scheduled vmcnt).  Only B is LDS-staged (gl16,
// double-buffered, one __syncthreads per phase = m97-proven drain pattern).
// LDS 33/41 KB, 4-wave blocks, 128 x {128|160} tile, BK=64.
// Binary: single acc; at half-K fold k=sqrt(ss_r/ss_l) into acc; epilogue *sr.
template<int MODE>
__global__ __launch_bounds__(256, 3) void gemm_fused(
    const u16* __restrict__ Asrc, const int* __restrict__ lidx,
    const int* __restrict__ ridx, const u16* __restrict__ Wb,
    const float* __restrict__ bias, const u16* __restrict__ Cin,
    float* __restrict__ sumsq, u16* __restrict__ H, u16* __restrict__ C,
    int sbase, int step)
{
  constexpr int NG  = (MODE==0) ? 1 : (MODE==1 ? 4 : 5);
  constexpr int NBR = (MODE==2) ? 160 : 128;   // B tile rows (= out cols)
  constexpr int NT  = (MODE==2) ? 8 : 4;       // K tiles of 64
  constexpr int WN  = (MODE==2) ? 80 : 64;     // wave col extent
  constexpr int NFR = WN/16;
  constexpr int GPW = NBR/32;                  // B granules (8 rows) per wave

  __shared__ u16 SB[2][NBR][64];               // 32/40 KB
  __shared__ float red[8];

  const int tid  = threadIdx.x;
  const int lane = tid & 63, wave = tid >> 6;
  const int mbase = blockIdx.x*128;
  const int nbase = blockIdx.y*NBR;
  const int l15 = lane & 15, kg = lane >> 4;
  const int wm = (wave >> 1)*64, wn = (wave & 1)*WN;

  // ---- A: per-lane child row byte offsets (frag rows are l15-indexed) ----
  u32 rbl[4], rbr[(MODE==2)?4:1];
  #pragma unroll
  for (int mi = 0; mi < 4; mi++){
    int r = mbase + wm + mi*16 + l15;
    int c;
    if constexpr (MODE==0) c = r; else c = lidx[sbase + r];
    rbl[mi] = (u32)c*512;
    if constexpr (MODE==2) rbr[mi] = (u32)ridx[sbase + r]*512;
  }

  // ---- B staging pointers (pre-swizzled source chunk, rule #21) ----
  const int rhi = lane >> 3;
  const int lc  = (lane & 7) ^ rhi;
  const u16* bP[GPW];
  #pragma unroll
  for (int g = 0; g < GPW; g++)
    bP[g] = Wb + (size_t)(nbase + (wave*GPW + g)*8 + rhi)*256 + lc*8;

  // ---- half-K rescale factors (binary) ----
  float kf[(MODE==2)?4:1][(MODE==2)?4:1];
  if constexpr (MODE==2){
    #pragma unroll
    for (int mi = 0; mi < 4; mi++)
      #pragma unroll
      for (int r = 0; r < 4; r++){
        int node = sbase + mbase + wm + mi*16 + kg*4 + r;
        kf[mi][r] = sqrtf(sumsq[ridx[node] >> 13] / sumsq[lidx[node] >> 13]);
      }
  }

  floatx4 acc[4][NFR];
  #pragma unroll
  for (int i = 0; i < 4; i++)
    #pragma unroll
    for (int j2 = 0; j2 < NFR; j2++) acc[i][j2] = (floatx4)(0.0f);

  auto stageB = [&](int t, int buf){
    size_t off;
    if constexpr (MODE==2) off = (t >= 4) ? (size_t)RHALF + (size_t)(t-4)*64 : (size_t)t*64;
    else                   off = (size_t)t*64;
    #pragma unroll
    for (int g = 0; g < GPW; g++)
      gl16(bP[g] + off, &SB[buf][(wave*GPW + g)*8][0]);
  };

  const char* Ab = (const char*)Asrc;

  stageB(0, 0);
  __syncthreads();                              // drains gl16 (vmcnt 0)

  #pragma unroll
  for (int t = 0; t < NT; t++){
    const int buf = t & 1;
    if (t + 1 < NT) stageB(t+1, buf^1);         // overlaps this phase's compute

    if constexpr (MODE==2){
      if (t == 4){                              // left half done: fold sl/sr
        #pragma unroll
        for (int mi = 0; mi < 4; mi++)
          #pragma unroll
          for (int r = 0; r < 4; r++){
            float k = kf[mi][r];
            #pragma unroll
            for (int ni = 0; ni < NFR; ni++) acc[mi][ni][r] *= k;
          }
      }
    }

    #pragma unroll
    for (int j = 0; j < 2; j++){
      shortx8 af[4];
      #pragma unroll
      for (int mi = 0; mi < 4; mi++){
        u32 rb; int ko;
        if constexpr (MODE==2){ rb = (t >= 4) ? rbr[mi] : rbl[mi]; ko = (t >= 4) ? t-4 : t; }
        else                  { rb = rbl[mi]; ko = t; }
        af[mi] = *reinterpret_cast<const shortx8*>(Ab + (size_t)rb + ko*128 + (j*4 + kg)*16);
      }
      shortx8 bfr[NFR];
      const int pc = ((j*4 + kg) ^ (l15 & 7)) * 8;
      #pragma unroll
      for (int n = 0; n < NFR; n++)
        bfr[n] = *reinterpret_cast<const shortx8*>(&SB[buf][wn + n*16 + l15][pc]);
      #pragma unroll
      for (int mi = 0; mi < 4; mi++)
        #pragma unroll
        for (int ni = 0; ni < NFR; ni++)
          acc[mi][ni] = __builtin_amdgcn_mfma_f32_16x16x32_bf16(af[mi], bfr[ni], acc[mi][ni], 0, 0, 0);
    }
    if (t + 1 < NT) __syncthreads();            // all reads done; B t+1 landed
  }

  // ---------------- fused epilogue ----------------
  if constexpr (MODE == 0){
    float bb[4];
    #pragma unroll
    for (int ni = 0; ni < 4; ni++) bb[ni] = bias[nbase + wn + ni*16 + l15];
    #pragma unroll
    for (int mi = 0; mi < 4; mi++){
      #pragma unroll
      for (int r = 0; r < 4; r++){
        int node = sbase + mbase + wm + mi*16 + kg*4 + r;
        u16* hp = H + (size_t)node*256 + nbase + wn + l15;
        u16* cp = C + (size_t)node*256 + nbase + wn + l15;
        #pragma unroll
        for (int ni = 0; ni < 4; ni++){
          hp[ni*16] = f2bfu(sigm(acc[mi][ni][r] + bb[ni]));
          cp[ni*16] = 0;
        }
      }
    }
  } else {
    const int e = (blockIdx.y*2 + (wave & 1))*16 + l15;
    float bb[NG];
    #pragma unroll
    for (int g = 0; g < NG; g++) bb[g] = bias[g*256 + e];
    float hss = 0.f, css = 0.f;
    #pragma unroll
    for (int mi = 0; mi < 4; mi++){
      #pragma unroll
      for (int r = 0; r < 4; r++){
        int node = sbase + mbase + wm + mi*16 + kg*4 + r;
        int chl = lidx[node];
        float cl = bfu2f(Cin[(size_t)chl*256 + e]) * invs(sumsq[16 + (chl >> 13)]);
        float c2, h2;
        if constexpr (MODE == 1){
          float sl = invs(sumsq[chl >> 13]);
          float i_ = sigm(acc[mi][0][r]*sl + bb[0]);
          float f_ = sigm(acc[mi][1][r]*sl + bb[1]);
          float o_ = sigm(acc[mi][2][r]*sl + bb[2]);
          float u_ = tanh_(acc[mi][3][r]*sl + bb[3]);
          c2 = i_*u_ + f_*cl;
          h2 = o_*tanh_(c2);
        } else {
          int chr = ridx[node];
          float sr = invs(sumsq[chr >> 13]);
          float cr = bfu2f(Cin[(size_t)chr*256 + e]) * invs(sumsq[16 + (chr >> 13)]);
          float i_ = sigm(acc[mi][0][r]*sr + bb[0]);
          float fl = sigm(acc[mi][1][r]*sr + bb[1]);
          float fr = sigm(acc[mi][2][r]*sr + bb[2]);
          float o_ = sigm(acc[mi][3][r]*sr + bb[3]);
          float u_ = tanh_(acc[mi][4][r]*sr + bb[4]);
          c2 = i_*u_ + fl*cl + fr*cr;
          h2 = o_*tanh_(c2);
        }
        H[(size_t)node*256 + e] = f2bfu(h2);
        C[(size_t)node*256 + e] = f2bfu(c2);
        hss += h2*h2;
        css += c2*c2;
      }
    }
    #pragma unroll
    for (int o = 32; o; o >>= 1){ hss += __shfl_down(hss, o); css += __shfl_down(css, o); }
    if (lane == 0){ red[wave] = hss; red[4+wave] = css; }
    __syncthreads();
    if (tid == 0)  atomicAdd(&sumsq[step],      red[0]+red[1]+red[2]+red[3]);
    if (tid == 64) atomicAdd(&sumsq[16 + step], red[4]+red[5]+red[6]+red[7]);
  }
}

// ---------------------------------------------------------------- output: bf16->f32 with per-step H scale
__global__ __launch_bounds__(256) void out_kernel(
    const u16* __restrict__ H, const float* __restrict__ sumsq, float* __restrict__ out)
{
  size_t base = ((size_t)blockIdx.x*256 + threadIdx.x)*8;
  int n = (int)(base >> 8);
  float s = invs(sumsq[n >> 13]);
  const uint4 v = *reinterpret_cast<const uint4*>(H + base);
  float4 o0, o1;
  o0.x = bfu2f((u16)(v.x & 0xffff))*s; o0.y = bfu2f((u16)(v.x >> 16))*s;
  o0.z = bfu2f((u16)(v.y & 0xffff))*s; o0.w = bfu2f((u16)(v.y >> 16))*s;
  o1.x = bfu2f((u16)(v.z & 0xffff))*s; o1.y = bfu2f((u16)(v.z >> 16))*s;
  o1.z = bfu2f((u16)(v.w & 0xffff))*s; o1.w = bfu2f((u16)(v.w >> 16))*s;
  *reinterpret_cast<float4*>(out + base)     = o0;
  *reinterpret_cast<float4*>(out + base + 4) = o1;
}

// ---------------------------------------------------------------- host
extern "C" void kernel_launch(void* const* d_in, const int* in_sizes, int n_in,
                              void* d_out, int out_size, void* d_ws, size_t ws_size,
                              hipStream_t stream)
{
  const int*   tokens     = (const int*)d_in[0];
  const int*   lidx       = (const int*)d_in[1];
  const int*   ridx       = (const int*)d_in[2];
  const float* leaf_table = (const float*)d_in[6];
  const float* num_W1     = (const float*)d_in[7];
  const float* num_b1     = (const float*)d_in[8];
  const float* num_W2     = (const float*)d_in[9];
  const float* num_b2     = (const float*)d_in[10];
  const float* una_W      = (const float*)d_in[11];
  const float* una_b      = (const float*)d_in[12];
  const float* bin_W      = (const float*)d_in[13];
  const float* bin_b      = (const float*)d_in[14];

  // ws layout: H | wbu | wbb | wbn | h1 | sumsq
  char* ws = (char*)d_ws;
  size_t off = 0;
  u16* H   = (u16*)(ws + off); off += (size_t)N_TOTAL*256*2;
  u16* wbu = (u16*)(ws + off); off += (size_t)2048*256*2;
  u16* wbb = (u16*)(ws + off); off += (size_t)5120*256*2;
  u16* wbn = (u16*)(ws + off); off += (size_t)256*256*2;
  u16* h1  = (u16*)(ws + off); off += (size_t)G_STEP*256*2;
  float* sumsq = (float*)(ws + off); off += 32*4;

  u16* C = (u16*)d_out;  // dead before out_kernel overwrites

  setup_kernel<<<4001, 256, 0, stream>>>(tokens, leaf_table, num_W1, num_b1,
                                         una_W, bin_W, num_W2,
                                         wbu, wbb, wbn, h1, H, C, sumsq);
  gemm_fused<0><<<dim3(64, 2), 256, 0, stream>>>(
      h1, nullptr, nullptr, wbn, num_b2, nullptr, sumsq, H, C, G_STEP, 1);

  const int sched[16] = {-1,-2,0,2,1,3,0,2,1,3,0,2,1,3,0,2};
  for (int d = 2; d < 16; d++){
    int op = sched[d];
    int sbase = d*G_STEP;
    if (op == 0 || op == 1){
      gemm_fused<1><<<dim3(64, 8), 256, 0, stream>>>(
          H, lidx, nullptr, wbu + (size_t)op*1024*256,
          una_b + (size_t)op*4*256, C, sumsq, H, C, sbase, d);
    } else {
      int o2 = op - 2;
      gemm_fused<2><<<dim3(64, 8), 256, 0, stream>>>(
          H, lidx, ridx, wbb + (size_t)o2*2*1280*256,
          bin_b + (size_t)o2*5*256, C, sumsq, H, C, sbase, d);
    }
  }
  out_kernel<<<(N_TOTAL*256)/(256*8), 256, 0, stream>>>(H, sumsq, (float*)d_out);
}

// Round 13
// 608.795 us; speedup vs baseline: 1.1669x; 1.1669x over previous
//
#include <hip/hip_runtime.h>
#include <hip/hip_bf16.h>
#include <cstdint>

typedef unsigned short u16;
typedef unsigned int u32;
typedef __attribute__((ext_vector_type(4))) float floatx4;
typedef __attribute__((ext_vector_type(8))) short shortx8;

#define G_STEP 8192
#define N_TOTAL 131072
#define RHALF (1280*256)

__device__ __forceinline__ float bfu2f(u16 x){ return __uint_as_float(((unsigned)x)<<16); }
__device__ __forceinline__ u16 f2bfu(float x){ __hip_bfloat16 b = __float2bfloat16(x); return *reinterpret_cast<u16*>(&b); }
__device__ __forceinline__ float sigm(float x){ return 1.0f/(1.0f+__expf(-x)); }
__device__ __forceinline__ float tanh_(float x){
  float cx = fminf(fmaxf(x,-15.f),15.f);
  float e = __expf(2.f*cx);
  return (e-1.f)/(e+1.f);
}
__device__ __forceinline__ float invs(float x){ return 1.0f/sqrtf(x); }

__device__ __forceinline__ void gl16(const void* g, void* l){
  __builtin_amdgcn_global_load_lds((const __attribute__((address_space(1))) u32*)g,
                                   (__attribute__((address_space(3))) u32*)l, 16, 0, 0);
}

__device__ __forceinline__ void cvt8(const float* __restrict__ src, u16* __restrict__ dst){
  float4 a = *reinterpret_cast<const float4*>(src);
  float4 b = *reinterpret_cast<const float4*>(src+4);
  ushort4 o0; o0.x=f2bfu(a.x); o0.y=f2bfu(a.y); o0.z=f2bfu(a.z); o0.w=f2bfu(a.w);
  ushort4 o1; o1.x=f2bfu(b.x); o1.y=f2bfu(b.y); o1.z=f2bfu(b.z); o1.w=f2bfu(b.w);
  *reinterpret_cast<ushort4*>(dst)   = o0;
  *reinterpret_cast<ushort4*>(dst+4) = o1;
}

// ---------------------------------------------------------------- setup (fused prep + leaf + num_pre + sumsq init)
__global__ __launch_bounds__(256) void setup_kernel(
    const int* __restrict__ tokens, const float* __restrict__ leaf_table,
    const float* __restrict__ W1, const float* __restrict__ b1,
    const float* __restrict__ una_W, const float* __restrict__ bin_W,
    const float* __restrict__ num_W2,
    u16* __restrict__ wbu, u16* __restrict__ wbb, u16* __restrict__ wbn,
    u16* __restrict__ h1, u16* __restrict__ H, u16* __restrict__ C,
    float* __restrict__ sumsq)
{
  const int b = blockIdx.x, tid = threadIdx.x;
  if (b < 256){                                  // wbu: 2048 rows
    int row = b*8 + (tid>>5), d0 = (tid&31)*8;
    int op = row>>10, w = row&1023;
    int gate = (w>>4)&3, e = ((w>>6)<<4) | (w&15);
    cvt8(una_W + (size_t)((op*4+gate)*256 + e)*256 + d0, wbu + (size_t)row*256 + d0);
  } else if (b < 896){                           // wbb: 5120 rows
    int row = (b-256)*8 + (tid>>5), d0 = (tid&31)*8;
    int ob = row / 2560, rem = row - ob*2560;
    int lr = rem / 1280, rw = rem - lr*1280;
    int eblk = rw / 80, rem2 = rw - eblk*80;
    int gate = rem2 >> 4, el = rem2 & 15;
    int e = eblk*16 + el;
    cvt8(bin_W + (size_t)((ob*10 + 2*gate + lr)*256 + e)*256 + d0, wbb + (size_t)row*256 + d0);
  } else if (b < 928){                           // wbn: 256 rows plain
    int row = (b-896)*8 + (tid>>5), d0 = (tid&31)*8;
    cvt8(num_W2 + (size_t)row*256 + d0, wbn + (size_t)row*256 + d0);
  } else if (b < 2976){                          // leaf: 8192 nodes, 4/block
    int wave = tid >> 6, lane = tid & 63;
    int node = (b-928)*4 + wave;
    int t = tokens[node];
    const float4 e4 = *reinterpret_cast<const float4*>(leaf_table + (size_t)t*256 + lane*4);
    float ss = e4.x*e4.x + e4.y*e4.y + e4.z*e4.z + e4.w*e4.w;
    #pragma unroll
    for (int o = 32; o; o >>= 1) ss += __shfl_down(ss, o);
    ss = __shfl(ss, 0);
    float scale = fminf(1.0f, 1.0f/(sqrtf(ss) + 1e-7f));
    ushort4 hv;
    hv.x = f2bfu(e4.x*scale); hv.y = f2bfu(e4.y*scale);
    hv.z = f2bfu(e4.z*scale); hv.w = f2bfu(e4.w*scale);
    ushort4 zv; zv.x = zv.y = zv.z = zv.w = 0;
    *reinterpret_cast<ushort4*>(H + (size_t)node*256 + lane*4) = hv;
    *reinterpret_cast<ushort4*>(C + (size_t)node*256 + lane*4) = zv;
  } else if (b < 4000){                          // num_pre: 2M elems, 8/thread
    int flat = (b-2976)*2048 + tid*8;
    int n = flat >> 8, d0 = flat & 255;
    float x = (float)tokens[G_STEP + n];
    float4 w0 = *reinterpret_cast<const float4*>(W1 + d0);
    float4 w1 = *reinterpret_cast<const float4*>(W1 + d0 + 4);
    float4 c0 = *reinterpret_cast<const float4*>(b1 + d0);
    float4 c1 = *reinterpret_cast<const float4*>(b1 + d0 + 4);
    ushort4 o0, o1;
    o0.x = f2bfu(sigm(x*w0.x + c0.x)); o0.y = f2bfu(sigm(x*w0.y + c0.y));
    o0.z = f2bfu(sigm(x*w0.z + c0.z)); o0.w = f2bfu(sigm(x*w0.w + c0.w));
    o1.x = f2bfu(sigm(x*w1.x + c1.x)); o1.y = f2bfu(sigm(x*w1.y + c1.y));
    o1.z = f2bfu(sigm(x*w1.z + c1.z)); o1.w = f2bfu(sigm(x*w1.w + c1.w));
    *reinterpret_cast<ushort4*>(h1 + flat)     = o0;
    *reinterpret_cast<ushort4*>(h1 + flat + 4) = o1;
  } else {                                       // sumsq init
    if (tid < 32) sumsq[tid] = ((tid & 15) < 2) ? 1.0f : 0.0f;
  }
}

// ---------------------------------------------------------------- fused GEMM + LSTM cell, deferred H-norm
// A-DIRECT + REGISTER DOUBLE-BUFFER: A fragments prefetched one phase ahead
// (global->VGPR ping-pong), so the per-phase __syncthreads (vmcnt(0) drain)
// guarantees they've landed -- zero exposed latency (R12's failure mode).
// Only B is LDS-staged (gl16, dbuf).  LDS-pipe load per phase drops ~45%.
// 4-wave blocks, 128 x {128|160} tile, BK=64.
// Binary: single acc; fold k=sqrt(ss_r/ss_l) into acc at half-K; epilogue *sr.
template<int MODE>
__global__ __launch_bounds__(256, 2) void gemm_fused(
    const u16* __restrict__ Asrc, const int* __restrict__ lidx,
    const int* __restrict__ ridx, const u16* __restrict__ Wb,
    const float* __restrict__ bias, const u16* __restrict__ Cin,
    float* __restrict__ sumsq, u16* __restrict__ H, u16* __restrict__ C,
    int sbase, int step)
{
  constexpr int NG  = (MODE==0) ? 1 : (MODE==1 ? 4 : 5);
  constexpr int NBR = (MODE==2) ? 160 : 128;   // B tile rows (= out cols)
  constexpr int NT  = (MODE==2) ? 8 : 4;       // K tiles of 64
  constexpr int WN  = (MODE==2) ? 80 : 64;     // wave col extent
  constexpr int NFR = WN/16;
  constexpr int GPW = NBR/32;                  // B granules (8 rows) per wave

  __shared__ u16 SB[2][NBR][64];               // 32/40 KB
  __shared__ float red[8];

  const int tid  = threadIdx.x;
  const int lane = tid & 63, wave = tid >> 6;
  const int mbase = blockIdx.x*128;
  const int nbase = blockIdx.y*NBR;
  const int l15 = lane & 15, kg = lane >> 4;
  const int wm = (wave >> 1)*64, wn = (wave & 1)*WN;

  // ---- A: per-lane child row byte offsets (frag rows are l15-indexed) ----
  u32 rbl[4], rbr[(MODE==2)?4:1];
  #pragma unroll
  for (int mi = 0; mi < 4; mi++){
    int r = mbase + wm + mi*16 + l15;
    int c;
    if constexpr (MODE==0) c = r; else c = lidx[sbase + r];
    rbl[mi] = (u32)c*512;
    if constexpr (MODE==2) rbr[mi] = (u32)ridx[sbase + r]*512;
  }

  // ---- B staging pointers (pre-swizzled source chunk, rule #21) ----
  const int rhi = lane >> 3;
  const int lc  = (lane & 7) ^ rhi;
  const u16* bP[GPW];
  #pragma unroll
  for (int g = 0; g < GPW; g++)
    bP[g] = Wb + (size_t)(nbase + (wave*GPW + g)*8 + rhi)*256 + lc*8;

  // ---- half-K rescale factors (binary) ----
  float kf[(MODE==2)?4:1][(MODE==2)?4:1];
  if constexpr (MODE==2){
    #pragma unroll
    for (int mi = 0; mi < 4; mi++)
      #pragma unroll
      for (int r = 0; r < 4; r++){
        int node = sbase + mbase + wm + mi*16 + kg*4 + r;
        kf[mi][r] = sqrtf(sumsq[ridx[node] >> 13] / sumsq[lidx[node] >> 13]);
      }
  }

  floatx4 acc[4][NFR];
  #pragma unroll
  for (int i = 0; i < 4; i++)
    #pragma unroll
    for (int j2 = 0; j2 < NFR; j2++) acc[i][j2] = (floatx4)(0.0f);

  const char* Ab = (const char*)Asrc;

  auto stageB = [&](int t, int buf){
    size_t off;
    if constexpr (MODE==2) off = (t >= 4) ? (size_t)RHALF + (size_t)(t-4)*64 : (size_t)t*64;
    else                   off = (size_t)t*64;
    #pragma unroll
    for (int g = 0; g < GPW; g++)
      gl16(bP[g] + off, &SB[buf][(wave*GPW + g)*8][0]);
  };
  auto loadA = [&](shortx8* dst, int t){
    #pragma unroll
    for (int j = 0; j < 2; j++)
      #pragma unroll
      for (int mi = 0; mi < 4; mi++){
        u32 rb; int ko;
        if constexpr (MODE==2){ rb = (t >= 4) ? rbr[mi] : rbl[mi]; ko = (t >= 4) ? t-4 : t; }
        else                  { rb = rbl[mi]; ko = t; }
        dst[j*4 + mi] = *reinterpret_cast<const shortx8*>(Ab + (size_t)rb + ko*128 + (j*4 + kg)*16);
      }
  };

  shortx8 afA[8], afB[8];                      // ping-pong A fragments

  // prologue: A(0) -> afA, stage B(0); barrier drains both (vmcnt 0)
  loadA(afA, 0);
  stageB(0, 0);
  __syncthreads();

  #pragma unroll
  for (int t = 0; t < NT; t++){
    const int buf = t & 1;
    if (t + 1 < NT){
      loadA((t & 1) ? afA : afB, t+1);         // into the idle reg set
      stageB(t+1, buf^1);                      // into the idle LDS buf
    }

    if constexpr (MODE==2){
      if (t == 4){                             // left half done: fold sl/sr
        #pragma unroll
        for (int mi = 0; mi < 4; mi++)
          #pragma unroll
          for (int r = 0; r < 4; r++){
            float k = kf[mi][r];
            #pragma unroll
            for (int ni = 0; ni < NFR; ni++) acc[mi][ni][r] *= k;
          }
      }
    }

    #pragma unroll
    for (int j = 0; j < 2; j++){
      shortx8 bfr[NFR];
      const int pc = ((j*4 + kg) ^ (l15 & 7)) * 8;
      #pragma unroll
      for (int n = 0; n < NFR; n++)
        bfr[n] = *reinterpret_cast<const shortx8*>(&SB[buf][wn + n*16 + l15][pc]);
      #pragma unroll
      for (int mi = 0; mi < 4; mi++){
        shortx8 a = (t & 1) ? afB[j*4 + mi] : afA[j*4 + mi];
        #pragma unroll
        for (int ni = 0; ni < NFR; ni++)
          acc[mi][ni] = __builtin_amdgcn_mfma_f32_16x16x32_bf16(a, bfr[ni], acc[mi][ni], 0, 0, 0);
      }
    }
    if (t + 1 < NT) __syncthreads();           // drains A(t+1) prefetch + B(t+1)
  }

  // ---------------- fused epilogue ----------------
  if constexpr (MODE == 0){
    float bb[4];
    #pragma unroll
    for (int ni = 0; ni < 4; ni++) bb[ni] = bias[nbase + wn + ni*16 + l15];
    #pragma unroll
    for (int mi = 0; mi < 4; mi++){
      #pragma unroll
      for (int r = 0; r < 4; r++){
        int node = sbase + mbase + wm + mi*16 + kg*4 + r;
        u16* hp = H + (size_t)node*256 + nbase + wn + l15;
        u16* cp = C + (size_t)node*256 + nbase + wn + l15;
        #pragma unroll
        for (int ni = 0; ni < 4; ni++){
          hp[ni*16] = f2bfu(sigm(acc[mi][ni][r] + bb[ni]));
          cp[ni*16] = 0;
        }
      }
    }
  } else {
    const int e = (blockIdx.y*2 + (wave & 1))*16 + l15;
    float bb[NG];
    #pragma unroll
    for (int g = 0; g < NG; g++) bb[g] = bias[g*256 + e];
    float hss = 0.f, css = 0.f;
    #pragma unroll
    for (int mi = 0; mi < 4; mi++){
      #pragma unroll
      for (int r = 0; r < 4; r++){
        int node = sbase + mbase + wm + mi*16 + kg*4 + r;
        int chl = lidx[node];
        float cl = bfu2f(Cin[(size_t)chl*256 + e]) * invs(sumsq[16 + (chl >> 13)]);
        float c2, h2;
        if constexpr (MODE == 1){
          float sl = invs(sumsq[chl >> 13]);
          float i_ = sigm(acc[mi][0][r]*sl + bb[0]);
          float f_ = sigm(acc[mi][1][r]*sl + bb[1]);
          float o_ = sigm(acc[mi][2][r]*sl + bb[2]);
          float u_ = tanh_(acc[mi][3][r]*sl + bb[3]);
          c2 = i_*u_ + f_*cl;
          h2 = o_*tanh_(c2);
        } else {
          int chr = ridx[node];
          float sr = invs(sumsq[chr >> 13]);
          float cr = bfu2f(Cin[(size_t)chr*256 + e]) * invs(sumsq[16 + (chr >> 13)]);
          float i_ = sigm(acc[mi][0][r]*sr + bb[0]);
          float fl = sigm(acc[mi][1][r]*sr + bb[1]);
          float fr = sigm(acc[mi][2][r]*sr + bb[2]);
          float o_ = sigm(acc[mi][3][r]*sr + bb[3]);
          float u_ = tanh_(acc[mi][4][r]*sr + bb[4]);
          c2 = i_*u_ + fl*cl + fr*cr;
          h2 = o_*tanh_(c2);
        }
        H[(size_t)node*256 + e] = f2bfu(h2);
        C[(size_t)node*256 + e] = f2bfu(c2);
        hss += h2*h2;
        css += c2*c2;
      }
    }
    #pragma unroll
    for (int o = 32; o; o >>= 1){ hss += __shfl_down(hss, o); css += __shfl_down(css, o); }
    if (lane == 0){ red[wave] = hss; red[4+wave] = css; }
    __syncthreads();
    if (tid == 0)  atomicAdd(&sumsq[step],      red[0]+red[1]+red[2]+red[3]);
    if (tid == 64) atomicAdd(&sumsq[16 + step], red[4]+red[5]+red[6]+red[7]);
  }
}

// ---------------------------------------------------------------- output: bf16->f32 with per-step H scale
__global__ __launch_bounds__(256) void out_kernel(
    const u16* __restrict__ H, const float* __restrict__ sumsq, float* __restrict__ out)
{
  size_t base = ((size_t)blockIdx.x*256 + threadIdx.x)*8;
  int n = (int)(base >> 8);
  float s = invs(sumsq[n >> 13]);
  const uint4 v = *reinterpret_cast<const uint4*>(H + base);
  float4 o0, o1;
  o0.x = bfu2f((u16)(v.x & 0xffff))*s; o0.y = bfu2f((u16)(v.x >> 16))*s;
  o0.z = bfu2f((u16)(v.y & 0xffff))*s; o0.w = bfu2f((u16)(v.y >> 16))*s;
  o1.x = bfu2f((u16)(v.z & 0xffff))*s; o1.y = bfu2f((u16)(v.z >> 16))*s;
  o1.z = bfu2f((u16)(v.w & 0xffff))*s; o1.w = bfu2f((u16)(v.w >> 16))*s;
  *reinterpret_cast<float4*>(out + base)     = o0;
  *reinterpret_cast<float4*>(out + base + 4) = o1;
}

// ---------------------------------------------------------------- host
extern "C" void kernel_launch(void* const* d_in, const int* in_sizes, int n_in,
                              void* d_out, int out_size, void* d_ws, size_t ws_size,
                              hipStream_t stream)
{
  const int*   tokens     = (const int*)d_in[0];
  const int*   lidx       = (const int*)d_in[1];
  const int*   ridx       = (const int*)d_in[2];
  const float* leaf_table = (const float*)d_in[6];
  const float* num_W1     = (const float*)d_in[7];
  const float* num_b1     = (const float*)d_in[8];
  const float* num_W2     = (const float*)d_in[9];
  const float* num_b2     = (const float*)d_in[10];
  const float* una_W      = (const float*)d_in[11];
  const float* una_b      = (const float*)d_in[12];
  const float* bin_W      = (const float*)d_in[13];
  const float* bin_b      = (const float*)d_in[14];

  // ws layout: H | wbu | wbb | wbn | h1 | sumsq
  char* ws = (char*)d_ws;
  size_t off = 0;
  u16* H   = (u16*)(ws + off); off += (size_t)N_TOTAL*256*2;
  u16* wbu = (u16*)(ws + off); off += (size_t)2048*256*2;
  u16* wbb = (u16*)(ws + off); off += (size_t)5120*256*2;
  u16* wbn = (u16*)(ws + off); off += (size_t)256*256*2;
  u16* h1  = (u16*)(ws + off); off += (size_t)G_STEP*256*2;
  float* sumsq = (float*)(ws + off); off += 32*4;

  u16* C = (u16*)d_out;  // dead before out_kernel overwrites

  setup_kernel<<<4001, 256, 0, stream>>>(tokens, leaf_table, num_W1, num_b1,
                                         una_W, bin_W, num_W2,
                                         wbu, wbb, wbn, h1, H, C, sumsq);
  gemm_fused<0><<<dim3(64, 2), 256, 0, stream>>>(
      h1, nullptr, nullptr, wbn, num_b2, nullptr, sumsq, H, C, G_STEP, 1);

  const int sched[16] = {-1,-2,0,2,1,3,0,2,1,3,0,2,1,3,0,2};
  for (int d = 2; d < 16; d++){
    int op = sched[d];
    int sbase = d*G_STEP;
    if (op == 0 || op == 1){
      gemm_fused<1><<<dim3(64, 8), 256, 0, stream>>>(
          H, lidx, nullptr, wbu + (size_t)op*1024*256,
          una_b + (size_t)op*4*256, C, sumsq, H, C, sbase, d);
    } else {
      int o2 = op - 2;
      gemm_fused<2><<<dim3(64, 8), 256, 0, stream>>>(
          H, lidx, ridx, wbb + (size_t)o2*2*1280*256,
          bin_b + (size_t)o2*5*256, C, sumsq, H, C, sbase, d);
    }
  }
  out_kernel<<<(N_TOTAL*256)/(256*8), 256, 0, stream>>>(H, sumsq, (float*)d_out);
}

// Round 14
// 466.512 us; speedup vs baseline: 1.5228x; 1.3050x over previous
//
#include <hip/hip_runtime.h>
#include <hip/hip_bf16.h>
#include <cstdint>

typedef unsigned short u16;
typedef unsigned int u32;
typedef __attribute__((ext_vector_type(4))) float floatx4;
typedef __attribute__((ext_vector_type(8))) short shortx8;

#define G_STEP 8192
#define N_TOTAL 131072
#define RHALF (1280*256)

__device__ __forceinline__ float bfu2f(u16 x){ return __uint_as_float(((unsigned)x)<<16); }
__device__ __forceinline__ u16 f2bfu(float x){ __hip_bfloat16 b = __float2bfloat16(x); return *reinterpret_cast<u16*>(&b); }
__device__ __forceinline__ float sigm(float x){ return 1.0f/(1.0f+__expf(-x)); }
__device__ __forceinline__ float tanh_(float x){
  float cx = fminf(fmaxf(x,-15.f),15.f);
  float e = __expf(2.f*cx);
  return (e-1.f)/(e+1.f);
}
__device__ __forceinline__ float invs(float x){ return 1.0f/sqrtf(x); }

__device__ __forceinline__ void gl16(const void* g, void* l){
  __builtin_amdgcn_global_load_lds((const __attribute__((address_space(1))) u32*)g,
                                   (__attribute__((address_space(3))) u32*)l, 16, 0, 0);
}

// combined end-of-phase waits: lgkmcnt(0) always, vmcnt counted
template<int V> __device__ __forceinline__ void wait_vml();
template<> __device__ __forceinline__ void wait_vml<0>(){ asm volatile("s_waitcnt vmcnt(0) lgkmcnt(0)" ::: "memory"); }
template<> __device__ __forceinline__ void wait_vml<6>(){ asm volatile("s_waitcnt vmcnt(6) lgkmcnt(0)" ::: "memory"); }
template<> __device__ __forceinline__ void wait_vml<7>(){ asm volatile("s_waitcnt vmcnt(7) lgkmcnt(0)" ::: "memory"); }
template<> __device__ __forceinline__ void wait_vml<12>(){ asm volatile("s_waitcnt vmcnt(12) lgkmcnt(0)" ::: "memory"); }
template<> __device__ __forceinline__ void wait_vml<14>(){ asm volatile("s_waitcnt vmcnt(14) lgkmcnt(0)" ::: "memory"); }

__device__ __forceinline__ void cvt8(const float* __restrict__ src, u16* __restrict__ dst){
  float4 a = *reinterpret_cast<const float4*>(src);
  float4 b = *reinterpret_cast<const float4*>(src+4);
  ushort4 o0; o0.x=f2bfu(a.x); o0.y=f2bfu(a.y); o0.z=f2bfu(a.z); o0.w=f2bfu(a.w);
  ushort4 o1; o1.x=f2bfu(b.x); o1.y=f2bfu(b.y); o1.z=f2bfu(b.z); o1.w=f2bfu(b.w);
  *reinterpret_cast<ushort4*>(dst)   = o0;
  *reinterpret_cast<ushort4*>(dst+4) = o1;
}

// ---------------------------------------------------------------- setup (fused prep + leaf + num_pre + sumsq init)
__global__ __launch_bounds__(256) void setup_kernel(
    const int* __restrict__ tokens, const float* __restrict__ leaf_table,
    const float* __restrict__ W1, const float* __restrict__ b1,
    const float* __restrict__ una_W, const float* __restrict__ bin_W,
    const float* __restrict__ num_W2,
    u16* __restrict__ wbu, u16* __restrict__ wbb, u16* __restrict__ wbn,
    u16* __restrict__ h1, u16* __restrict__ H, u16* __restrict__ C,
    float* __restrict__ sumsq)
{
  const int b = blockIdx.x, tid = threadIdx.x;
  if (b < 256){                                  // wbu: 2048 rows
    int row = b*8 + (tid>>5), d0 = (tid&31)*8;
    int op = row>>10, w = row&1023;
    int gate = (w>>4)&3, e = ((w>>6)<<4) | (w&15);
    cvt8(una_W + (size_t)((op*4+gate)*256 + e)*256 + d0, wbu + (size_t)row*256 + d0);
  } else if (b < 896){                           // wbb: 5120 rows
    int row = (b-256)*8 + (tid>>5), d0 = (tid&31)*8;
    int ob = row / 2560, rem = row - ob*2560;
    int lr = rem / 1280, rw = rem - lr*1280;
    int eblk = rw / 80, rem2 = rw - eblk*80;
    int gate = rem2 >> 4, el = rem2 & 15;
    int e = eblk*16 + el;
    cvt8(bin_W + (size_t)((ob*10 + 2*gate + lr)*256 + e)*256 + d0, wbb + (size_t)row*256 + d0);
  } else if (b < 928){                           // wbn: 256 rows plain
    int row = (b-896)*8 + (tid>>5), d0 = (tid&31)*8;
    cvt8(num_W2 + (size_t)row*256 + d0, wbn + (size_t)row*256 + d0);
  } else if (b < 2976){                          // leaf: 8192 nodes, 4/block
    int wave = tid >> 6, lane = tid & 63;
    int node = (b-928)*4 + wave;
    int t = tokens[node];
    const float4 e4 = *reinterpret_cast<const float4*>(leaf_table + (size_t)t*256 + lane*4);
    float ss = e4.x*e4.x + e4.y*e4.y + e4.z*e4.z + e4.w*e4.w;
    #pragma unroll
    for (int o = 32; o; o >>= 1) ss += __shfl_down(ss, o);
    ss = __shfl(ss, 0);
    float scale = fminf(1.0f, 1.0f/(sqrtf(ss) + 1e-7f));
    ushort4 hv;
    hv.x = f2bfu(e4.x*scale); hv.y = f2bfu(e4.y*scale);
    hv.z = f2bfu(e4.z*scale); hv.w = f2bfu(e4.w*scale);
    ushort4 zv; zv.x = zv.y = zv.z = zv.w = 0;
    *reinterpret_cast<ushort4*>(H + (size_t)node*256 + lane*4) = hv;
    *reinterpret_cast<ushort4*>(C + (size_t)node*256 + lane*4) = zv;
  } else if (b < 4000){                          // num_pre: 2M elems, 8/thread
    int flat = (b-2976)*2048 + tid*8;
    int n = flat >> 8, d0 = flat & 255;
    float x = (float)tokens[G_STEP + n];
    float4 w0 = *reinterpret_cast<const float4*>(W1 + d0);
    float4 w1 = *reinterpret_cast<const float4*>(W1 + d0 + 4);
    float4 c0 = *reinterpret_cast<const float4*>(b1 + d0);
    float4 c1 = *reinterpret_cast<const float4*>(b1 + d0 + 4);
    ushort4 o0, o1;
    o0.x = f2bfu(sigm(x*w0.x + c0.x)); o0.y = f2bfu(sigm(x*w0.y + c0.y));
    o0.z = f2bfu(sigm(x*w0.z + c0.z)); o0.w = f2bfu(sigm(x*w0.w + c0.w));
    o1.x = f2bfu(sigm(x*w1.x + c1.x)); o1.y = f2bfu(sigm(x*w1.y + c1.y));
    o1.z = f2bfu(sigm(x*w1.z + c1.z)); o1.w = f2bfu(sigm(x*w1.w + c1.w));
    *reinterpret_cast<ushort4*>(h1 + flat)     = o0;
    *reinterpret_cast<ushort4*>(h1 + flat + 4) = o1;
  } else {                                       // sumsq init
    if (tid < 32) sumsq[tid] = ((tid & 15) < 2) ? 1.0f : 0.0f;
  }
}

// ---------------------------------------------------------------- fused GEMM + LSTM cell, deferred H-norm
// R10 base (8-wave 512-thread, 256-row tiles, BK=64, triple-buffered LDS, one
// barrier/phase) + R14 polish: 3-deep prologue (stage 0..2 issued before first
// wait), hoisted child indices (kf + epilogue share one load), setprio around
// MFMA clusters.  Split accL/accR (exact R5 numerics).
template<int MODE>
__global__ __launch_bounds__(512, 2) void gemm_fused(
    const u16* __restrict__ Asrc, const int* __restrict__ lidx,
    const int* __restrict__ ridx, const u16* __restrict__ Wb,
    const float* __restrict__ bias, const u16* __restrict__ Cin,
    float* __restrict__ sumsq, u16* __restrict__ H, u16* __restrict__ C,
    int sbase, int step)
{
  constexpr int NG  = (MODE==0) ? 1 : (MODE==1 ? 4 : 5);
  constexpr int NBR = (MODE==2) ? 160 : 128;   // B tile rows (= out cols)
  constexpr int NT  = (MODE==2) ? 8 : 4;       // K tiles of 64
  constexpr int WN  = (MODE==2) ? 80 : 64;     // wave col extent
  constexpr int NFR = WN/16;
  constexpr int NBG = NBR/8;                   // B granules (8 rows each)

  __shared__ u16 SA[3][256][64];               // 96 KB
  __shared__ u16 SB[3][NBR][64];               // 48/60 KB
  __shared__ float red[16];

  const int tid  = threadIdx.x;
  const int lane = tid & 63, wave = tid >> 6;

  const int bid = blockIdx.x;
  const int jj  = bid >> 3;
  const int bx  = (bid & 7) + 8*(jj & 3);      // [0,32)
  const int by  = jj >> 2;
  const int mbase = bx*256;
  const int nbase = by*NBR;

  const int l15 = lane & 15, kg = lane >> 4;
  const int wm = (wave >> 1)*64, wn = (wave & 1)*WN;

  // staging geometry: one gl16 = 8 rows x 64 cols; lane l -> row g*8+(l>>3),
  // phys chunk l&7, source logical chunk (l&7)^(l>>3)  [pre-swizzle, rule #21]
  const int rhi = lane >> 3;
  const int lc  = (lane & 7) ^ rhi;

  // ---- hoisted per-output child indices (epilogue + kf share) ----
  int chl_[4][4];
  int chr_[(MODE==2)?4:1][(MODE==2)?4:1];
  float kf[(MODE==2)?4:1][(MODE==2)?4:1];
  if constexpr (MODE != 0){
    #pragma unroll
    for (int mi = 0; mi < 4; mi++)
      #pragma unroll
      for (int r = 0; r < 4; r++){
        int node = sbase + mbase + wm + mi*16 + kg*4 + r;
        chl_[mi][r] = lidx[node];
        if constexpr (MODE==2){
          chr_[mi][r] = ridx[node];
          kf[mi][r] = sqrtf(sumsq[chr_[mi][r] >> 13] / sumsq[chl_[mi][r] >> 13]);
        }
      }
  }

  // A granules: 32 total, 4 per wave
  const u16* aL[4]; const u16* aR[4];
  #pragma unroll
  for (int g = 0; g < 4; g++){
    int r = (wave*4 + g)*8 + rhi;
    int gr;
    if constexpr (MODE==0) gr = mbase + r;
    else                   gr = lidx[sbase + mbase + r];
    aL[g] = Asrc + (size_t)gr*256 + lc*8;
    if constexpr (MODE==2)
      aR[g] = Asrc + (size_t)ridx[sbase + mbase + r]*256 + lc*8;
  }
  // B granules: NBG total (16 or 20); waves 0-3 take 3 (MODE2), others 2
  const int nbg_w = (MODE==2) ? ((wave < 4) ? 3 : 2) : 2;
  const int bg0   = (MODE==2) ? ((wave < 4) ? wave*3 : 12 + (wave-4)*2) : wave*2;
  const u16* bP[3];
  #pragma unroll
  for (int g = 0; g < 3; g++){
    int gg = bg0 + g;
    if (gg >= NBG) gg = NBG-1;                  // harmless dup for unused slot
    bP[g] = Wb + (size_t)(nbase + gg*8 + rhi)*256 + lc*8;
  }

  floatx4 accL[4][NFR];
  #pragma unroll
  for (int i = 0; i < 4; i++)
    #pragma unroll
    for (int j2 = 0; j2 < NFR; j2++) accL[i][j2] = (floatx4)(0.0f);
  floatx4 accR[(MODE==2)?4:1][(MODE==2)?NFR:1];
  if constexpr (MODE==2){
    #pragma unroll
    for (int i = 0; i < 4; i++)
      #pragma unroll
      for (int j2 = 0; j2 < NFR; j2++) accR[i][j2] = (floatx4)(0.0f);
  }

  auto stage = [&](int t){
    const int slot = t % 3;                    // t is unroll-constant
    const int kk = t*64;
    #pragma unroll
    for (int g = 0; g < 4; g++){
      const u16* ga;
      if constexpr (MODE==2){ ga = (kk >= 256) ? aR[g] + (kk-256) : aL[g] + kk; }
      else                  { ga = aL[g] + kk; }
      gl16(ga, &SA[slot][(wave*4 + g)*8][0]);
    }
    #pragma unroll
    for (int g = 0; g < 3; g++){
      if (g < nbg_w){
        const u16* gb;
        if constexpr (MODE==2){ gb = (kk >= 256) ? bP[g] + RHALF + (kk-256) : bP[g] + kk; }
        else                  { gb = bP[g] + kk; }
        gl16(gb, &SB[slot][(bg0 + g)*8][0]);
      }
    }
  };

  // prologue: 3-deep prefetch (slots 0,1,2); wait for stage(0) only
  stage(0);
  stage(1);
  stage(2);
  if (MODE==2 && wave < 4) wait_vml<14>(); else wait_vml<12>();
  __builtin_amdgcn_s_barrier();

  #pragma unroll
  for (int t = 0; t < NT; t++){
    const int slot = t % 3;
    if (t >= 1 && t + 2 < NT) stage(t+2);      // into (t+2)%3 (t=0 covered by prologue)

    // j = 0
    {
      shortx8 af[4], bfr[NFR];
      const int pc = (kg ^ (l15 & 7)) * 8;
      #pragma unroll
      for (int i = 0; i < 4; i++)
        af[i] = *reinterpret_cast<const shortx8*>(&SA[slot][wm + i*16 + l15][pc]);
      #pragma unroll
      for (int n = 0; n < NFR; n++)
        bfr[n] = *reinterpret_cast<const shortx8*>(&SB[slot][wn + n*16 + l15][pc]);
      __builtin_amdgcn_s_setprio(1);
      if (MODE==2 && t >= 4){
        #pragma unroll
        for (int mi = 0; mi < 4; mi++)
          #pragma unroll
          for (int ni = 0; ni < NFR; ni++)
            accR[mi][ni] = __builtin_amdgcn_mfma_f32_16x16x32_bf16(af[mi], bfr[ni], accR[mi][ni], 0, 0, 0);
      } else {
        #pragma unroll
        for (int mi = 0; mi < 4; mi++)
          #pragma unroll
          for (int ni = 0; ni < NFR; ni++)
            accL[mi][ni] = __builtin_amdgcn_mfma_f32_16x16x32_bf16(af[mi], bfr[ni], accL[mi][ni], 0, 0, 0);
      }
      __builtin_amdgcn_s_setprio(0);
    }
    // j = 1
    {
      shortx8 af[4], bfr[NFR];
      const int pc = ((4 + kg) ^ (l15 & 7)) * 8;
      #pragma unroll
      for (int i = 0; i < 4; i++)
        af[i] = *reinterpret_cast<const shortx8*>(&SA[slot][wm + i*16 + l15][pc]);
      #pragma unroll
      for (int n = 0; n < NFR; n++)
        bfr[n] = *reinterpret_cast<const shortx8*>(&SB[slot][wn + n*16 + l15][pc]);
      __builtin_amdgcn_s_setprio(1);
      if (MODE==2 && t >= 4){
        #pragma unroll
        for (int mi = 0; mi < 4; mi++)
          #pragma unroll
          for (int ni = 0; ni < NFR; ni++)
            accR[mi][ni] = __builtin_amdgcn_mfma_f32_16x16x32_bf16(af[mi], bfr[ni], accR[mi][ni], 0, 0, 0);
      } else {
        #pragma unroll
        for (int mi = 0; mi < 4; mi++)
          #pragma unroll
          for (int ni = 0; ni < NFR; ni++)
            accL[mi][ni] = __builtin_amdgcn_mfma_f32_16x16x32_bf16(af[mi], bfr[ni], accL[mi][ni], 0, 0, 0);
      }
      __builtin_amdgcn_s_setprio(0);
    }

    // end of phase: my reads in regs (lgkm0), stage(t+1) landed (vmcnt), join.
    if (t + 1 < NT){
      if (t + 2 < NT){
        if (MODE==2 && wave < 4) wait_vml<7>(); else wait_vml<6>();
      } else wait_vml<0>();
      __builtin_amdgcn_s_barrier();
    }
  }

  // ---------------- fused epilogue ----------------
  if constexpr (MODE == 0){
    float bb[4];
    #pragma unroll
    for (int ni = 0; ni < 4; ni++) bb[ni] = bias[nbase + wn + ni*16 + l15];
    #pragma unroll
    for (int mi = 0; mi < 4; mi++){
      #pragma unroll
      for (int r = 0; r < 4; r++){
        int node = sbase + mbase + wm + mi*16 + kg*4 + r;
        u16* hp = H + (size_t)node*256 + nbase + wn + l15;
        u16* cp = C + (size_t)node*256 + nbase + wn + l15;
        #pragma unroll
        for (int ni = 0; ni < 4; ni++){
          hp[ni*16] = f2bfu(sigm(accL[mi][ni][r] + bb[ni]));
          cp[ni*16] = 0;
        }
      }
    }
  } else {
    const int e = (by*2 + (wave & 1))*16 + l15;
    float bb[NG];
    #pragma unroll
    for (int g = 0; g < NG; g++) bb[g] = bias[g*256 + e];
    float hss = 0.f, css = 0.f;
    #pragma unroll
    for (int mi = 0; mi < 4; mi++){
      #pragma unroll
      for (int r = 0; r < 4; r++){
        int node = sbase + mbase + wm + mi*16 + kg*4 + r;
        int chl = chl_[mi][r];
        float sl = invs(sumsq[chl >> 13]);
        float cl = bfu2f(Cin[(size_t)chl*256 + e]) * invs(sumsq[16 + (chl >> 13)]);
        float c2, h2;
        if constexpr (MODE == 1){
          float i_ = sigm(accL[mi][0][r]*sl + bb[0]);
          float f_ = sigm(accL[mi][1][r]*sl + bb[1]);
          float o_ = sigm(accL[mi][2][r]*sl + bb[2]);
          float u_ = tanh_(accL[mi][3][r]*sl + bb[3]);
          c2 = i_*u_ + f_*cl;
          h2 = o_*tanh_(c2);
        } else {
          int chr = chr_[mi][r];
          float sr = invs(sumsq[chr >> 13]);
          float cr = bfu2f(Cin[(size_t)chr*256 + e]) * invs(sumsq[16 + (chr >> 13)]);
          float g0 = accL[mi][0][r]*sl + accR[mi][0][r]*sr + bb[0];
          float g1 = accL[mi][1][r]*sl + accR[mi][1][r]*sr + bb[1];
          float g2 = accL[mi][2][r]*sl + accR[mi][2][r]*sr + bb[2];
          float g3 = accL[mi][3][r]*sl + accR[mi][3][r]*sr + bb[3];
          float g4 = accL[mi][4][r]*sl + accR[mi][4][r]*sr + bb[4];
          float i_ = sigm(g0);
          float fl = sigm(g1);
          float fr = sigm(g2);
          float o_ = sigm(g3);
          float u_ = tanh_(g4);
          c2 = i_*u_ + fl*cl + fr*cr;
          h2 = o_*tanh_(c2);
        }
        H[(size_t)node*256 + e] = f2bfu(h2);
        C[(size_t)node*256 + e] = f2bfu(c2);
        hss += h2*h2;
        css += c2*c2;
      }
    }
    #pragma unroll
    for (int o = 32; o; o >>= 1){ hss += __shfl_down(hss, o); css += __shfl_down(css, o); }
    if (lane == 0){ red[wave] = hss; red[8+wave] = css; }
    __syncthreads();
    if (tid == 0){
      float s = 0.f;
      #pragma unroll
      for (int w = 0; w < 8; w++) s += red[w];
      atomicAdd(&sumsq[step], s);
    }
    if (tid == 64){
      float s = 0.f;
      #pragma unroll
      for (int w = 0; w < 8; w++) s += red[8+w];
      atomicAdd(&sumsq[16 + step], s);
    }
  }
}

// ---------------------------------------------------------------- output: bf16->f32 with per-step H scale
__global__ __launch_bounds__(256) void out_kernel(
    const u16* __restrict__ H, const float* __restrict__ sumsq, float* __restrict__ out)
{
  size_t base = ((size_t)blockIdx.x*256 + threadIdx.x)*8;
  int n = (int)(base >> 8);
  float s = invs(sumsq[n >> 13]);
  const uint4 v = *reinterpret_cast<const uint4*>(H + base);
  float4 o0, o1;
  o0.x = bfu2f((u16)(v.x & 0xffff))*s; o0.y = bfu2f((u16)(v.x >> 16))*s;
  o0.z = bfu2f((u16)(v.y & 0xffff))*s; o0.w = bfu2f((u16)(v.y >> 16))*s;
  o1.x = bfu2f((u16)(v.z & 0xffff))*s; o1.y = bfu2f((u16)(v.z >> 16))*s;
  o1.z = bfu2f((u16)(v.w & 0xffff))*s; o1.w = bfu2f((u16)(v.w >> 16))*s;
  *reinterpret_cast<float4*>(out + base)     = o0;
  *reinterpret_cast<float4*>(out + base + 4) = o1;
}

// ---------------------------------------------------------------- host
extern "C" void kernel_launch(void* const* d_in, const int* in_sizes, int n_in,
                              void* d_out, int out_size, void* d_ws, size_t ws_size,
                              hipStream_t stream)
{
  const int*   tokens     = (const int*)d_in[0];
  const int*   lidx       = (const int*)d_in[1];
  const int*   ridx       = (const int*)d_in[2];
  const float* leaf_table = (const float*)d_in[6];
  const float* num_W1     = (const float*)d_in[7];
  const float* num_b1     = (const float*)d_in[8];
  const float* num_W2     = (const float*)d_in[9];
  const float* num_b2     = (const float*)d_in[10];
  const float* una_W      = (const float*)d_in[11];
  const float* una_b      = (const float*)d_in[12];
  const float* bin_W      = (const float*)d_in[13];
  const float* bin_b      = (const float*)d_in[14];

  // ws layout: H | wbu | wbb | wbn | h1 | sumsq | C   (~142 MB; ws >= 512 MB
  // per harness fill evidence WRITE_SIZE=524288 KB)
  char* ws = (char*)d_ws;
  size_t off = 0;
  u16* H   = (u16*)(ws + off); off += (size_t)N_TOTAL*256*2;
  u16* wbu = (u16*)(ws + off); off += (size_t)2048*256*2;
  u16* wbb = (u16*)(ws + off); off += (size_t)5120*256*2;
  u16* wbn = (u16*)(ws + off); off += (size_t)256*256*2;
  u16* h1  = (u16*)(ws + off); off += (size_t)G_STEP*256*2;
  float* sumsq = (float*)(ws + off); off += 256;   // padded
  u16* C   = (u16*)(ws + off); off += (size_t)N_TOTAL*256*2;

  setup_kernel<<<4001, 256, 0, stream>>>(tokens, leaf_table, num_W1, num_b1,
                                         una_W, bin_W, num_W2,
                                         wbu, wbb, wbn, h1, H, C, sumsq);
  gemm_fused<0><<<64, 512, 0, stream>>>(
      h1, nullptr, nullptr, wbn, num_b2, nullptr, sumsq, H, C, G_STEP, 1);

  const int sched[16] = {-1,-2,0,2,1,3,0,2,1,3,0,2,1,3,0,2};
  for (int d = 2; d < 16; d++){
    int op = sched[d];
    int sbase = d*G_STEP;
    if (op == 0 || op == 1){
      gemm_fused<1><<<256, 512, 0, stream>>>(
          H, lidx, nullptr, wbu + (size_t)op*1024*256,
          una_b + (size_t)op*4*256, C, sumsq, H, C, sbase, d);
    } else {
      int o2 = op - 2;
      gemm_fused<2><<<256, 512, 0, stream>>>(
          H, lidx, ridx, wbb + (size_t)o2*2*1280*256,
          bin_b + (size_t)o2*5*256, C, sumsq, H, C, sbase, d);
    }
  }
  out_kernel<<<(N_TOTAL*256)/(256*8), 256, 0, stream>>>(H, sumsq, (float*)d_out);
}

// Round 15
// 434.388 us; speedup vs baseline: 1.6354x; 1.0740x over previous
//
#include <hip/hip_runtime.h>
#include <hip/hip_bf16.h>
#include <cstdint>

typedef unsigned short u16;
typedef unsigned int u32;
typedef __attribute__((ext_vector_type(4))) float floatx4;
typedef __attribute__((ext_vector_type(8))) short shortx8;

#define G_STEP 8192
#define N_TOTAL 131072
#define RHALF (1280*256)

__device__ __forceinline__ float bfu2f(u16 x){ return __uint_as_float(((unsigned)x)<<16); }
__device__ __forceinline__ u16 f2bfu(float x){ __hip_bfloat16 b = __float2bfloat16(x); return *reinterpret_cast<u16*>(&b); }
__device__ __forceinline__ float sigm(float x){ return 1.0f/(1.0f+__expf(-x)); }
__device__ __forceinline__ float tanh_(float x){
  float cx = fminf(fmaxf(x,-15.f),15.f);
  float e = __expf(2.f*cx);
  return (e-1.f)/(e+1.f);
}
__device__ __forceinline__ float invs(float x){ return 1.0f/sqrtf(x); }

__device__ __forceinline__ void gl16(const void* g, void* l){
  __builtin_amdgcn_global_load_lds((const __attribute__((address_space(1))) u32*)g,
                                   (__attribute__((address_space(3))) u32*)l, 16, 0, 0);
}

// combined end-of-phase waits: lgkmcnt(0) always, vmcnt counted
template<int V> __device__ __forceinline__ void wait_vml();
template<> __device__ __forceinline__ void wait_vml<0>(){ asm volatile("s_waitcnt vmcnt(0) lgkmcnt(0)" ::: "memory"); }
template<> __device__ __forceinline__ void wait_vml<6>(){ asm volatile("s_waitcnt vmcnt(6) lgkmcnt(0)" ::: "memory"); }
template<> __device__ __forceinline__ void wait_vml<7>(){ asm volatile("s_waitcnt vmcnt(7) lgkmcnt(0)" ::: "memory"); }

__device__ __forceinline__ void cvt8(const float* __restrict__ src, u16* __restrict__ dst){
  float4 a = *reinterpret_cast<const float4*>(src);
  float4 b = *reinterpret_cast<const float4*>(src+4);
  ushort4 o0; o0.x=f2bfu(a.x); o0.y=f2bfu(a.y); o0.z=f2bfu(a.z); o0.w=f2bfu(a.w);
  ushort4 o1; o1.x=f2bfu(b.x); o1.y=f2bfu(b.y); o1.z=f2bfu(b.z); o1.w=f2bfu(b.w);
  *reinterpret_cast<ushort4*>(dst)   = o0;
  *reinterpret_cast<ushort4*>(dst+4) = o1;
}

// ---------------------------------------------------------------- setup (fused prep + leaf + num_pre + sumsq init)
__global__ __launch_bounds__(256) void setup_kernel(
    const int* __restrict__ tokens, const float* __restrict__ leaf_table,
    const float* __restrict__ W1, const float* __restrict__ b1,
    const float* __restrict__ una_W, const float* __restrict__ bin_W,
    const float* __restrict__ num_W2,
    u16* __restrict__ wbu, u16* __restrict__ wbb, u16* __restrict__ wbn,
    u16* __restrict__ h1, u16* __restrict__ H, u16* __restrict__ C,
    float* __restrict__ sumsq)
{
  const int b = blockIdx.x, tid = threadIdx.x;
  if (b < 256){                                  // wbu: 2048 rows
    int row = b*8 + (tid>>5), d0 = (tid&31)*8;
    int op = row>>10, w = row&1023;
    int gate = (w>>4)&3, e = ((w>>6)<<4) | (w&15);
    cvt8(una_W + (size_t)((op*4+gate)*256 + e)*256 + d0, wbu + (size_t)row*256 + d0);
  } else if (b < 896){                           // wbb: 5120 rows
    int row = (b-256)*8 + (tid>>5), d0 = (tid&31)*8;
    int ob = row / 2560, rem = row - ob*2560;
    int lr = rem / 1280, rw = rem - lr*1280;
    int eblk = rw / 80, rem2 = rw - eblk*80;
    int gate = rem2 >> 4, el = rem2 & 15;
    int e = eblk*16 + el;
    cvt8(bin_W + (size_t)((ob*10 + 2*gate + lr)*256 + e)*256 + d0, wbb + (size_t)row*256 + d0);
  } else if (b < 928){                           // wbn: 256 rows plain
    int row = (b-896)*8 + (tid>>5), d0 = (tid&31)*8;
    cvt8(num_W2 + (size_t)row*256 + d0, wbn + (size_t)row*256 + d0);
  } else if (b < 2976){                          // leaf: 8192 nodes, 4/block
    int wave = tid >> 6, lane = tid & 63;
    int node = (b-928)*4 + wave;
    int t = tokens[node];
    const float4 e4 = *reinterpret_cast<const float4*>(leaf_table + (size_t)t*256 + lane*4);
    float ss = e4.x*e4.x + e4.y*e4.y + e4.z*e4.z + e4.w*e4.w;
    #pragma unroll
    for (int o = 32; o; o >>= 1) ss += __shfl_down(ss, o);
    ss = __shfl(ss, 0);
    float scale = fminf(1.0f, 1.0f/(sqrtf(ss) + 1e-7f));
    ushort4 hv;
    hv.x = f2bfu(e4.x*scale); hv.y = f2bfu(e4.y*scale);
    hv.z = f2bfu(e4.z*scale); hv.w = f2bfu(e4.w*scale);
    ushort4 zv; zv.x = zv.y = zv.z = zv.w = 0;
    *reinterpret_cast<ushort4*>(H + (size_t)node*256 + lane*4) = hv;
    *reinterpret_cast<ushort4*>(C + (size_t)node*256 + lane*4) = zv;
  } else if (b < 4000){                          // num_pre: 2M elems, 8/thread
    int flat = (b-2976)*2048 + tid*8;
    int n = flat >> 8, d0 = flat & 255;
    float x = (float)tokens[G_STEP + n];
    float4 w0 = *reinterpret_cast<const float4*>(W1 + d0);
    float4 w1 = *reinterpret_cast<const float4*>(W1 + d0 + 4);
    float4 c0 = *reinterpret_cast<const float4*>(b1 + d0);
    float4 c1 = *reinterpret_cast<const float4*>(b1 + d0 + 4);
    ushort4 o0, o1;
    o0.x = f2bfu(sigm(x*w0.x + c0.x)); o0.y = f2bfu(sigm(x*w0.y + c0.y));
    o0.z = f2bfu(sigm(x*w0.z + c0.z)); o0.w = f2bfu(sigm(x*w0.w + c0.w));
    o1.x = f2bfu(sigm(x*w1.x + c1.x)); o1.y = f2bfu(sigm(x*w1.y + c1.y));
    o1.z = f2bfu(sigm(x*w1.z + c1.z)); o1.w = f2bfu(sigm(x*w1.w + c1.w));
    *reinterpret_cast<ushort4*>(h1 + flat)     = o0;
    *reinterpret_cast<ushort4*>(h1 + flat + 4) = o1;
  } else {                                       // sumsq init
    if (tid < 32) sumsq[tid] = ((tid & 15) < 2) ? 1.0f : 0.0f;
  }
}

// ---------------------------------------------------------------- fused GEMM + LSTM cell, deferred H-norm
// 8-wave 512-thread blocks, 256-row tiles, BK=64, TRIPLE-buffered LDS with ONE
// barrier per phase: stage(t+2) at phase top targets slot (t+2)%3 (neither the
// slot being read t%3 nor t+1's), so no mid-phase guard is needed.  End of
// phase: lgkmcnt(0) (my reads in regs) + counted vmcnt (stage t+1 landed) +
// s_barrier.  Split accL/accR (exact R5 numerics).  Epilogue child indices
// loaded AFTER the K-loop (keeps loop VGPR pressure low -- R14 regression
// proved hoisting them spills).
template<int MODE>
__global__ __launch_bounds__(512, 2) void gemm_fused(
    const u16* __restrict__ Asrc, const int* __restrict__ lidx,
    const int* __restrict__ ridx, const u16* __restrict__ Wb,
    const float* __restrict__ bias, const u16* __restrict__ Cin,
    float* __restrict__ sumsq, u16* __restrict__ H, u16* __restrict__ C,
    int sbase, int step)
{
  constexpr int NG  = (MODE==0) ? 1 : (MODE==1 ? 4 : 5);
  constexpr int NBR = (MODE==2) ? 160 : 128;   // B tile rows (= out cols)
  constexpr int NT  = (MODE==2) ? 8 : 4;       // K tiles of 64
  constexpr int WN  = (MODE==2) ? 80 : 64;     // wave col extent
  constexpr int NFR = WN/16;
  constexpr int NBG = NBR/8;                   // B granules (8 rows each)

  __shared__ u16 SA[3][256][64];               // 96 KB
  __shared__ u16 SB[3][NBR][64];               // 48/60 KB
  __shared__ float red[16];

  const int tid  = threadIdx.x;
  const int lane = tid & 63, wave = tid >> 6;

  const int bid = blockIdx.x;
  const int jj  = bid >> 3;
  const int bx  = (bid & 7) + 8*(jj & 3);      // [0,32)
  const int by  = jj >> 2;
  const int mbase = bx*256;
  const int nbase = by*NBR;

  const int l15 = lane & 15, kg = lane >> 4;
  const int wm = (wave >> 1)*64, wn = (wave & 1)*WN;

  // staging geometry: one gl16 = 8 rows x 64 cols; lane l -> row g*8+(l>>3),
  // phys chunk l&7, source logical chunk (l&7)^(l>>3)  [pre-swizzle, rule #21]
  const int rhi = lane >> 3;
  const int lc  = (lane & 7) ^ rhi;

  // A granules: 32 total, 4 per wave
  const u16* aL[4]; const u16* aR[4];
  #pragma unroll
  for (int g = 0; g < 4; g++){
    int r = (wave*4 + g)*8 + rhi;
    int gr;
    if constexpr (MODE==0) gr = mbase + r;
    else                   gr = lidx[sbase + mbase + r];
    aL[g] = Asrc + (size_t)gr*256 + lc*8;
    if constexpr (MODE==2)
      aR[g] = Asrc + (size_t)ridx[sbase + mbase + r]*256 + lc*8;
  }
  // B granules: NBG total (16 or 20); waves 0-3 take 3 (MODE2), others 2
  const int nbg_w = (MODE==2) ? ((wave < 4) ? 3 : 2) : 2;
  const int bg0   = (MODE==2) ? ((wave < 4) ? wave*3 : 12 + (wave-4)*2) : wave*2;
  const u16* bP[3];
  #pragma unroll
  for (int g = 0; g < 3; g++){
    int gg = bg0 + g;
    if (gg >= NBG) gg = NBG-1;                  // harmless dup for unused slot
    bP[g] = Wb + (size_t)(nbase + gg*8 + rhi)*256 + lc*8;
  }

  floatx4 accL[4][NFR];
  #pragma unroll
  for (int i = 0; i < 4; i++)
    #pragma unroll
    for (int j2 = 0; j2 < NFR; j2++) accL[i][j2] = (floatx4)(0.0f);
  floatx4 accR[(MODE==2)?4:1][(MODE==2)?NFR:1];
  if constexpr (MODE==2){
    #pragma unroll
    for (int i = 0; i < 4; i++)
      #pragma unroll
      for (int j2 = 0; j2 < NFR; j2++) accR[i][j2] = (floatx4)(0.0f);
  }

  auto stage = [&](int t){
    const int slot = t % 3;                    // t is unroll-constant
    const int kk = t*64;
    #pragma unroll
    for (int g = 0; g < 4; g++){
      const u16* ga;
      if constexpr (MODE==2){ ga = (kk >= 256) ? aR[g] + (kk-256) : aL[g] + kk; }
      else                  { ga = aL[g] + kk; }
      gl16(ga, &SA[slot][(wave*4 + g)*8][0]);
    }
    #pragma unroll
    for (int g = 0; g < 3; g++){
      if (g < nbg_w){
        const u16* gb;
        if constexpr (MODE==2){ gb = (kk >= 256) ? bP[g] + RHALF + (kk-256) : bP[g] + kk; }
        else                  { gb = bP[g] + kk; }
        gl16(gb, &SB[slot][(bg0 + g)*8][0]);
      }
    }
  };

  // prologue: 2-deep prefetch; wait for stage(0) (idx loads older, also drained)
  stage(0);
  stage(1);
  if (MODE==2 && wave < 4) wait_vml<7>(); else wait_vml<6>();
  __builtin_amdgcn_s_barrier();

  #pragma unroll
  for (int t = 0; t < NT; t++){
    const int slot = t % 3;
    if (t + 2 < NT) stage(t+2);                // into (t+2)%3: no reader conflict

    // j = 0
    {
      shortx8 af[4], bfr[NFR];
      const int pc = (kg ^ (l15 & 7)) * 8;
      #pragma unroll
      for (int i = 0; i < 4; i++)
        af[i] = *reinterpret_cast<const shortx8*>(&SA[slot][wm + i*16 + l15][pc]);
      #pragma unroll
      for (int n = 0; n < NFR; n++)
        bfr[n] = *reinterpret_cast<const shortx8*>(&SB[slot][wn + n*16 + l15][pc]);
      if (MODE==2 && t >= 4){
        #pragma unroll
        for (int mi = 0; mi < 4; mi++)
          #pragma unroll
          for (int ni = 0; ni < NFR; ni++)
            accR[mi][ni] = __builtin_amdgcn_mfma_f32_16x16x32_bf16(af[mi], bfr[ni], accR[mi][ni], 0, 0, 0);
      } else {
        #pragma unroll
        for (int mi = 0; mi < 4; mi++)
          #pragma unroll
          for (int ni = 0; ni < NFR; ni++)
            accL[mi][ni] = __builtin_amdgcn_mfma_f32_16x16x32_bf16(af[mi], bfr[ni], accL[mi][ni], 0, 0, 0);
      }
    }
    // j = 1
    {
      shortx8 af[4], bfr[NFR];
      const int pc = ((4 + kg) ^ (l15 & 7)) * 8;
      #pragma unroll
      for (int i = 0; i < 4; i++)
        af[i] = *reinterpret_cast<const shortx8*>(&SA[slot][wm + i*16 + l15][pc]);
      #pragma unroll
      for (int n = 0; n < NFR; n++)
        bfr[n] = *reinterpret_cast<const shortx8*>(&SB[slot][wn + n*16 + l15][pc]);
      if (MODE==2 && t >= 4){
        #pragma unroll
        for (int mi = 0; mi < 4; mi++)
          #pragma unroll
          for (int ni = 0; ni < NFR; ni++)
            accR[mi][ni] = __builtin_amdgcn_mfma_f32_16x16x32_bf16(af[mi], bfr[ni], accR[mi][ni], 0, 0, 0);
      } else {
        #pragma unroll
        for (int mi = 0; mi < 4; mi++)
          #pragma unroll
          for (int ni = 0; ni < NFR; ni++)
            accL[mi][ni] = __builtin_amdgcn_mfma_f32_16x16x32_bf16(af[mi], bfr[ni], accL[mi][ni], 0, 0, 0);
      }
    }

    // end of phase: my reads in regs (lgkm0), stage(t+1) landed (vmcnt), join.
    if (t + 1 < NT){
      if (t + 2 < NT){
        if (MODE==2 && wave < 4) wait_vml<7>(); else wait_vml<6>();
      } else wait_vml<0>();
      __builtin_amdgcn_s_barrier();
    }
  }

  // ---------------- fused epilogue ----------------
  if constexpr (MODE == 0){
    float bb[4];
    #pragma unroll
    for (int ni = 0; ni < 4; ni++) bb[ni] = bias[nbase + wn + ni*16 + l15];
    #pragma unroll
    for (int mi = 0; mi < 4; mi++){
      #pragma unroll
      for (int r = 0; r < 4; r++){
        int node = sbase + mbase + wm + mi*16 + kg*4 + r;
        u16* hp = H + (size_t)node*256 + nbase + wn + l15;
        u16* cp = C + (size_t)node*256 + nbase + wn + l15;
        #pragma unroll
        for (int ni = 0; ni < 4; ni++){
          hp[ni*16] = f2bfu(sigm(accL[mi][ni][r] + bb[ni]));
          cp[ni*16] = 0;
        }
      }
    }
  } else {
    const int e = (by*2 + (wave & 1))*16 + l15;
    float bb[NG];
    #pragma unroll
    for (int g = 0; g < NG; g++) bb[g] = bias[g*256 + e];
    float hss = 0.f, css = 0.f;
    #pragma unroll
    for (int mi = 0; mi < 4; mi++){
      #pragma unroll
      for (int r = 0; r < 4; r++){
        int orow = mbase + wm + mi*16 + kg*4 + r;
        int node = sbase + orow;
        int chl = lidx[node];
        float sl = invs(sumsq[chl >> 13]);
        float cl = bfu2f(Cin[(size_t)chl*256 + e]) * invs(sumsq[16 + (chl >> 13)]);
        float c2, h2;
        if constexpr (MODE == 1){
          float i_ = sigm(accL[mi][0][r]*sl + bb[0]);
          float f_ = sigm(accL[mi][1][r]*sl + bb[1]);
          float o_ = sigm(accL[mi][2][r]*sl + bb[2]);
          float u_ = tanh_(accL[mi][3][r]*sl + bb[3]);
          c2 = i_*u_ + f_*cl;
          h2 = o_*tanh_(c2);
        } else {
          int chr = ridx[node];
          float sr = invs(sumsq[chr >> 13]);
          float cr = bfu2f(Cin[(size_t)chr*256 + e]) * invs(sumsq[16 + (chr >> 13)]);
          float g0 = accL[mi][0][r]*sl + accR[mi][0][r]*sr + bb[0];
          float g1 = accL[mi][1][r]*sl + accR[mi][1][r]*sr + bb[1];
          float g2 = accL[mi][2][r]*sl + accR[mi][2][r]*sr + bb[2];
          float g3 = accL[mi][3][r]*sl + accR[mi][3][r]*sr + bb[3];
          float g4 = accL[mi][4][r]*sl + accR[mi][4][r]*sr + bb[4];
          float i_ = sigm(g0);
          float fl = sigm(g1);
          float fr = sigm(g2);
          float o_ = sigm(g3);
          float u_ = tanh_(g4);
          c2 = i_*u_ + fl*cl + fr*cr;
          h2 = o_*tanh_(c2);
        }
        H[(size_t)node*256 + e] = f2bfu(h2);
        C[(size_t)node*256 + e] = f2bfu(c2);
        hss += h2*h2;
        css += c2*c2;
      }
    }
    #pragma unroll
    for (int o = 32; o; o >>= 1){ hss += __shfl_down(hss, o); css += __shfl_down(css, o); }
    if (lane == 0){ red[wave] = hss; red[8+wave] = css; }
    __syncthreads();
    if (tid == 0){
      float s = 0.f;
      #pragma unroll
      for (int w = 0; w < 8; w++) s += red[w];
      atomicAdd(&sumsq[step], s);
    }
    if (tid == 64){
      float s = 0.f;
      #pragma unroll
      for (int w = 0; w < 8; w++) s += red[8+w];
      atomicAdd(&sumsq[16 + step], s);
    }
  }
}

// ---------------------------------------------------------------- output: bf16->f32 with per-step H scale
__global__ __launch_bounds__(256) void out_kernel(
    const u16* __restrict__ H, const float* __restrict__ sumsq, float* __restrict__ out)
{
  size_t base = ((size_t)blockIdx.x*256 + threadIdx.x)*8;
  int n = (int)(base >> 8);
  float s = invs(sumsq[n >> 13]);
  const uint4 v = *reinterpret_cast<const uint4*>(H + base);
  float4 o0, o1;
  o0.x = bfu2f((u16)(v.x & 0xffff))*s; o0.y = bfu2f((u16)(v.x >> 16))*s;
  o0.z = bfu2f((u16)(v.y & 0xffff))*s; o0.w = bfu2f((u16)(v.y >> 16))*s;
  o1.x = bfu2f((u16)(v.z & 0xffff))*s; o1.y = bfu2f((u16)(v.z >> 16))*s;
  o1.z = bfu2f((u16)(v.w & 0xffff))*s; o1.w = bfu2f((u16)(v.w >> 16))*s;
  *reinterpret_cast<float4*>(out + base)     = o0;
  *reinterpret_cast<float4*>(out + base + 4) = o1;
}

// ---------------------------------------------------------------- host
extern "C" void kernel_launch(void* const* d_in, const int* in_sizes, int n_in,
                              void* d_out, int out_size, void* d_ws, size_t ws_size,
                              hipStream_t stream)
{
  const int*   tokens     = (const int*)d_in[0];
  const int*   lidx       = (const int*)d_in[1];
  const int*   ridx       = (const int*)d_in[2];
  const float* leaf_table = (const float*)d_in[6];
  const float* num_W1     = (const float*)d_in[7];
  const float* num_b1     = (const float*)d_in[8];
  const float* num_W2     = (const float*)d_in[9];
  const float* num_b2     = (const float*)d_in[10];
  const float* una_W      = (const float*)d_in[11];
  const float* una_b      = (const float*)d_in[12];
  const float* bin_W      = (const float*)d_in[13];
  const float* bin_b      = (const float*)d_in[14];

  // ws layout: H | wbu | wbb | wbn | h1 | sumsq
  char* ws = (char*)d_ws;
  size_t off = 0;
  u16* H   = (u16*)(ws + off); off += (size_t)N_TOTAL*256*2;
  u16* wbu = (u16*)(ws + off); off += (size_t)2048*256*2;
  u16* wbb = (u16*)(ws + off); off += (size_t)5120*256*2;
  u16* wbn = (u16*)(ws + off); off += (size_t)256*256*2;
  u16* h1  = (u16*)(ws + off); off += (size_t)G_STEP*256*2;
  float* sumsq = (float*)(ws + off); off += 32*4;

  u16* C = (u16*)d_out;  // dead before out_kernel overwrites

  setup_kernel<<<4001, 256, 0, stream>>>(tokens, leaf_table, num_W1, num_b1,
                                         una_W, bin_W, num_W2,
                                         wbu, wbb, wbn, h1, H, C, sumsq);
  gemm_fused<0><<<64, 512, 0, stream>>>(
      h1, nullptr, nullptr, wbn, num_b2, nullptr, sumsq, H, C, G_STEP, 1);

  const int sched[16] = {-1,-2,0,2,1,3,0,2,1,3,0,2,1,3,0,2};
  for (int d = 2; d < 16; d++){
    int op = sched[d];
    int sbase = d*G_STEP;
    if (op == 0 || op == 1){
      gemm_fused<1><<<256, 512, 0, stream>>>(
          H, lidx, nullptr, wbu + (size_t)op*1024*256,
          una_b + (size_t)op*4*256, C, sumsq, H, C, sbase, d);
    } else {
      int o2 = op - 2;
      gemm_fused<2><<<256, 512, 0, stream>>>(
          H, lidx, ridx, wbb + (size_t)o2*2*1280*256,
          bin_b + (size_t)o2*5*256, C, sumsq, H, C, sbase, d);
    }
  }
  out_kernel<<<(N_TOTAL*256)/(256*8), 256, 0, stream>>>(H, sumsq, (float*)d_out);
}

// Round 16
// 362.482 us; speedup vs baseline: 1.9598x; 1.1984x over previous
//
#include <hip/hip_runtime.h>
#include <hip/hip_bf16.h>
#include <cstdint>

typedef unsigned short u16;
typedef unsigned int u32;
typedef __attribute__((ext_vector_type(4))) float floatx4;
typedef __attribute__((ext_vector_type(8))) short shortx8;

#define G_STEP 8192
#define N_TOTAL 131072
#define RHALF (1280*256)

__device__ __forceinline__ float bfu2f(u16 x){ return __uint_as_float(((unsigned)x)<<16); }
__device__ __forceinline__ u16 f2bfu(float x){ __hip_bfloat16 b = __float2bfloat16(x); return *reinterpret_cast<u16*>(&b); }
__device__ __forceinline__ float sigm(float x){ return 1.0f/(1.0f+__expf(-x)); }
__device__ __forceinline__ float tanh_(float x){
  float cx = fminf(fmaxf(x,-15.f),15.f);
  float e = __expf(2.f*cx);
  return (e-1.f)/(e+1.f);
}
__device__ __forceinline__ float invs(float x){ return 1.0f/sqrtf(x); }

__device__ __forceinline__ void gl16(const void* g, void* l){
  __builtin_amdgcn_global_load_lds((const __attribute__((address_space(1))) u32*)g,
                                   (__attribute__((address_space(3))) u32*)l, 16, 0, 0);
}

// combined end-of-phase waits: lgkmcnt(0) always, vmcnt counted
template<int V> __device__ __forceinline__ void wait_vml();
template<> __device__ __forceinline__ void wait_vml<0>(){ asm volatile("s_waitcnt vmcnt(0) lgkmcnt(0)" ::: "memory"); }
template<> __device__ __forceinline__ void wait_vml<6>(){ asm volatile("s_waitcnt vmcnt(6) lgkmcnt(0)" ::: "memory"); }
template<> __device__ __forceinline__ void wait_vml<7>(){ asm volatile("s_waitcnt vmcnt(7) lgkmcnt(0)" ::: "memory"); }

__device__ __forceinline__ void cvt8(const float* __restrict__ src, u16* __restrict__ dst){
  float4 a = *reinterpret_cast<const float4*>(src);
  float4 b = *reinterpret_cast<const float4*>(src+4);
  ushort4 o0; o0.x=f2bfu(a.x); o0.y=f2bfu(a.y); o0.z=f2bfu(a.z); o0.w=f2bfu(a.w);
  ushort4 o1; o1.x=f2bfu(b.x); o1.y=f2bfu(b.y); o1.z=f2bfu(b.z); o1.w=f2bfu(b.w);
  *reinterpret_cast<ushort4*>(dst)   = o0;
  *reinterpret_cast<ushort4*>(dst+4) = o1;
}

// ---------------------------------------------------------------- setup (fused prep + leaf + num_pre + sumsq init)
__global__ __launch_bounds__(256) void setup_kernel(
    const int* __restrict__ tokens, const float* __restrict__ leaf_table,
    const float* __restrict__ W1, const float* __restrict__ b1,
    const float* __restrict__ una_W, const float* __restrict__ bin_W,
    const float* __restrict__ num_W2,
    u16* __restrict__ wbu, u16* __restrict__ wbb, u16* __restrict__ wbn,
    u16* __restrict__ h1, u16* __restrict__ H, u16* __restrict__ C,
    float* __restrict__ sumsq)
{
  const int b = blockIdx.x, tid = threadIdx.x;
  if (b < 256){                                  // wbu: 2048 rows
    int row = b*8 + (tid>>5), d0 = (tid&31)*8;
    int op = row>>10, w = row&1023;
    int gate = (w>>4)&3, e = ((w>>6)<<4) | (w&15);
    cvt8(una_W + (size_t)((op*4+gate)*256 + e)*256 + d0, wbu + (size_t)row*256 + d0);
  } else if (b < 896){                           // wbb: 5120 rows
    int row = (b-256)*8 + (tid>>5), d0 = (tid&31)*8;
    int ob = row / 2560, rem = row - ob*2560;
    int lr = rem / 1280, rw = rem - lr*1280;
    int eblk = rw / 80, rem2 = rw - eblk*80;
    int gate = rem2 >> 4, el = rem2 & 15;
    int e = eblk*16 + el;
    cvt8(bin_W + (size_t)((ob*10 + 2*gate + lr)*256 + e)*256 + d0, wbb + (size_t)row*256 + d0);
  } else if (b < 928){                           // wbn: 256 rows plain
    int row = (b-896)*8 + (tid>>5), d0 = (tid&31)*8;
    cvt8(num_W2 + (size_t)row*256 + d0, wbn + (size_t)row*256 + d0);
  } else if (b < 2976){                          // leaf: 8192 nodes, 4/block
    int wave = tid >> 6, lane = tid & 63;
    int node = (b-928)*4 + wave;
    int t = tokens[node];
    const float4 e4 = *reinterpret_cast<const float4*>(leaf_table + (size_t)t*256 + lane*4);
    float ss = e4.x*e4.x + e4.y*e4.y + e4.z*e4.z + e4.w*e4.w;
    #pragma unroll
    for (int o = 32; o; o >>= 1) ss += __shfl_down(ss, o);
    ss = __shfl(ss, 0);
    float scale = fminf(1.0f, 1.0f/(sqrtf(ss) + 1e-7f));
    ushort4 hv;
    hv.x = f2bfu(e4.x*scale); hv.y = f2bfu(e4.y*scale);
    hv.z = f2bfu(e4.z*scale); hv.w = f2bfu(e4.w*scale);
    ushort4 zv; zv.x = zv.y = zv.z = zv.w = 0;
    *reinterpret_cast<ushort4*>(H + (size_t)node*256 + lane*4) = hv;
    *reinterpret_cast<ushort4*>(C + (size_t)node*256 + lane*4) = zv;
  } else if (b < 4000){                          // num_pre: 2M elems, 8/thread
    int flat = (b-2976)*2048 + tid*8;
    int n = flat >> 8, d0 = flat & 255;
    float x = (float)tokens[G_STEP + n];
    float4 w0 = *reinterpret_cast<const float4*>(W1 + d0);
    float4 w1 = *reinterpret_cast<const float4*>(W1 + d0 + 4);
    float4 c0 = *reinterpret_cast<const float4*>(b1 + d0);
    float4 c1 = *reinterpret_cast<const float4*>(b1 + d0 + 4);
    ushort4 o0, o1;
    o0.x = f2bfu(sigm(x*w0.x + c0.x)); o0.y = f2bfu(sigm(x*w0.y + c0.y));
    o0.z = f2bfu(sigm(x*w0.z + c0.z)); o0.w = f2bfu(sigm(x*w0.w + c0.w));
    o1.x = f2bfu(sigm(x*w1.x + c1.x)); o1.y = f2bfu(sigm(x*w1.y + c1.y));
    o1.z = f2bfu(sigm(x*w1.z + c1.z)); o1.w = f2bfu(sigm(x*w1.w + c1.w));
    *reinterpret_cast<ushort4*>(h1 + flat)     = o0;
    *reinterpret_cast<ushort4*>(h1 + flat + 4) = o1;
  } else {                                       // sumsq init
    if (tid < 32) sumsq[tid] = ((tid & 15) < 2) ? 1.0f : 0.0f;
  }
}

// ---------------------------------------------------------------- fused GEMM + LSTM cell, deferred H-norm
// R10 EXACT: 8-wave 512-thread blocks, 256-row tiles, BK=64, TRIPLE-buffered
// LDS with ONE barrier per phase; stage(t+2) at phase top targets slot
// (t+2)%3 (neither the slot being read t%3 nor t+1's).  End of phase:
// lgkmcnt(0) + counted vmcnt + s_barrier.  scH/scC invs-scales precomputed
// into LDS at block start (R15 regression proved global reads in the epilogue
// cost ~70us).  Split accL/accR.  Epilogue child indices loaded AFTER the
// K-loop (R14 regression proved hoisting them spills).
template<int MODE>
__global__ __launch_bounds__(512, 2) void gemm_fused(
    const u16* __restrict__ Asrc, const int* __restrict__ lidx,
    const int* __restrict__ ridx, const u16* __restrict__ Wb,
    const float* __restrict__ bias, const u16* __restrict__ Cin,
    float* __restrict__ sumsq, u16* __restrict__ H, u16* __restrict__ C,
    int sbase, int step)
{
  constexpr int NG  = (MODE==0) ? 1 : (MODE==1 ? 4 : 5);
  constexpr int NBR = (MODE==2) ? 160 : 128;   // B tile rows (= out cols)
  constexpr int NT  = (MODE==2) ? 8 : 4;       // K tiles of 64
  constexpr int WN  = (MODE==2) ? 80 : 64;     // wave col extent
  constexpr int NFR = WN/16;
  constexpr int NBG = NBR/8;                   // B granules (8 rows each)

  __shared__ u16 SA[3][256][64];               // 96 KB
  __shared__ u16 SB[3][NBR][64];               // 48/60 KB
  __shared__ float scH[16];
  __shared__ float scC[16];
  __shared__ float red[16];

  const int tid  = threadIdx.x;
  const int lane = tid & 63, wave = tid >> 6;

  const int bid = blockIdx.x;
  const int jj  = bid >> 3;
  const int bx  = (bid & 7) + 8*(jj & 3);      // [0,32)
  const int by  = jj >> 2;
  const int mbase = bx*256;
  const int nbase = by*NBR;

  const int l15 = lane & 15, kg = lane >> 4;
  const int wm = (wave >> 1)*64, wn = (wave & 1)*WN;

  if (MODE != 0){
    if (tid < 16)      scH[tid]    = invs(sumsq[tid]);
    else if (tid < 32) scC[tid-16] = invs(sumsq[tid]);
  }

  // staging geometry: one gl16 = 8 rows x 64 cols; lane l -> row g*8+(l>>3),
  // phys chunk l&7, source logical chunk (l&7)^(l>>3)  [pre-swizzle, rule #21]
  const int rhi = lane >> 3;
  const int lc  = (lane & 7) ^ rhi;

  // A granules: 32 total, 4 per wave
  const u16* aL[4]; const u16* aR[4];
  #pragma unroll
  for (int g = 0; g < 4; g++){
    int r = (wave*4 + g)*8 + rhi;
    int gr;
    if constexpr (MODE==0) gr = mbase + r;
    else                   gr = lidx[sbase + mbase + r];
    aL[g] = Asrc + (size_t)gr*256 + lc*8;
    if constexpr (MODE==2)
      aR[g] = Asrc + (size_t)ridx[sbase + mbase + r]*256 + lc*8;
  }
  // B granules: NBG total (16 or 20); waves 0-3 take 3 (MODE2), others 2
  const int nbg_w = (MODE==2) ? ((wave < 4) ? 3 : 2) : 2;
  const int bg0   = (MODE==2) ? ((wave < 4) ? wave*3 : 12 + (wave-4)*2) : wave*2;
  const u16* bP[3];
  #pragma unroll
  for (int g = 0; g < 3; g++){
    int gg = bg0 + g;
    if (gg >= NBG) gg = NBG-1;                  // harmless dup for unused slot
    bP[g] = Wb + (size_t)(nbase + gg*8 + rhi)*256 + lc*8;
  }

  floatx4 accL[4][NFR];
  #pragma unroll
  for (int i = 0; i < 4; i++)
    #pragma unroll
    for (int j2 = 0; j2 < NFR; j2++) accL[i][j2] = (floatx4)(0.0f);
  floatx4 accR[(MODE==2)?4:1][(MODE==2)?NFR:1];
  if constexpr (MODE==2){
    #pragma unroll
    for (int i = 0; i < 4; i++)
      #pragma unroll
      for (int j2 = 0; j2 < NFR; j2++) accR[i][j2] = (floatx4)(0.0f);
  }

  auto stage = [&](int t){
    const int slot = t % 3;                    // t is unroll-constant
    const int kk = t*64;
    #pragma unroll
    for (int g = 0; g < 4; g++){
      const u16* ga;
      if constexpr (MODE==2){ ga = (kk >= 256) ? aR[g] + (kk-256) : aL[g] + kk; }
      else                  { ga = aL[g] + kk; }
      gl16(ga, &SA[slot][(wave*4 + g)*8][0]);
    }
    #pragma unroll
    for (int g = 0; g < 3; g++){
      if (g < nbg_w){
        const u16* gb;
        if constexpr (MODE==2){ gb = (kk >= 256) ? bP[g] + RHALF + (kk-256) : bP[g] + kk; }
        else                  { gb = bP[g] + kk; }
        gl16(gb, &SB[slot][(bg0 + g)*8][0]);
      }
    }
  };

  // prologue: 2-deep prefetch; wait for stage(0) (idx loads older, also drained)
  stage(0);
  stage(1);
  if (MODE==2 && wave < 4) wait_vml<7>(); else wait_vml<6>();
  __builtin_amdgcn_s_barrier();

  #pragma unroll
  for (int t = 0; t < NT; t++){
    const int slot = t % 3;
    if (t + 2 < NT) stage(t+2);                // into (t+2)%3: no reader conflict

    // j = 0
    {
      shortx8 af[4], bfr[NFR];
      const int pc = (kg ^ (l15 & 7)) * 8;
      #pragma unroll
      for (int i = 0; i < 4; i++)
        af[i] = *reinterpret_cast<const shortx8*>(&SA[slot][wm + i*16 + l15][pc]);
      #pragma unroll
      for (int n = 0; n < NFR; n++)
        bfr[n] = *reinterpret_cast<const shortx8*>(&SB[slot][wn + n*16 + l15][pc]);
      if (MODE==2 && t >= 4){
        #pragma unroll
        for (int mi = 0; mi < 4; mi++)
          #pragma unroll
          for (int ni = 0; ni < NFR; ni++)
            accR[mi][ni] = __builtin_amdgcn_mfma_f32_16x16x32_bf16(af[mi], bfr[ni], accR[mi][ni], 0, 0, 0);
      } else {
        #pragma unroll
        for (int mi = 0; mi < 4; mi++)
          #pragma unroll
          for (int ni = 0; ni < NFR; ni++)
            accL[mi][ni] = __builtin_amdgcn_mfma_f32_16x16x32_bf16(af[mi], bfr[ni], accL[mi][ni], 0, 0, 0);
      }
    }
    // j = 1
    {
      shortx8 af[4], bfr[NFR];
      const int pc = ((4 + kg) ^ (l15 & 7)) * 8;
      #pragma unroll
      for (int i = 0; i < 4; i++)
        af[i] = *reinterpret_cast<const shortx8*>(&SA[slot][wm + i*16 + l15][pc]);
      #pragma unroll
      for (int n = 0; n < NFR; n++)
        bfr[n] = *reinterpret_cast<const shortx8*>(&SB[slot][wn + n*16 + l15][pc]);
      if (MODE==2 && t >= 4){
        #pragma unroll
        for (int mi = 0; mi < 4; mi++)
          #pragma unroll
          for (int ni = 0; ni < NFR; ni++)
            accR[mi][ni] = __builtin_amdgcn_mfma_f32_16x16x32_bf16(af[mi], bfr[ni], accR[mi][ni], 0, 0, 0);
      } else {
        #pragma unroll
        for (int mi = 0; mi < 4; mi++)
          #pragma unroll
          for (int ni = 0; ni < NFR; ni++)
            accL[mi][ni] = __builtin_amdgcn_mfma_f32_16x16x32_bf16(af[mi], bfr[ni], accL[mi][ni], 0, 0, 0);
      }
    }

    // end of phase: my reads in regs (lgkm0), stage(t+1) landed (vmcnt), join.
    if (t + 1 < NT){
      if (t + 2 < NT){
        if (MODE==2 && wave < 4) wait_vml<7>(); else wait_vml<6>();
      } else wait_vml<0>();
      __builtin_amdgcn_s_barrier();
    }
  }

  // ---------------- fused epilogue ----------------
  if constexpr (MODE == 0){
    float bb[4];
    #pragma unroll
    for (int ni = 0; ni < 4; ni++) bb[ni] = bias[nbase + wn + ni*16 + l15];
    #pragma unroll
    for (int mi = 0; mi < 4; mi++){
      #pragma unroll
      for (int r = 0; r < 4; r++){
        int node = sbase + mbase + wm + mi*16 + kg*4 + r;
        u16* hp = H + (size_t)node*256 + nbase + wn + l15;
        u16* cp = C + (size_t)node*256 + nbase + wn + l15;
        #pragma unroll
        for (int ni = 0; ni < 4; ni++){
          hp[ni*16] = f2bfu(sigm(accL[mi][ni][r] + bb[ni]));
          cp[ni*16] = 0;
        }
      }
    }
  } else {
    const int e = (by*2 + (wave & 1))*16 + l15;
    float bb[NG];
    #pragma unroll
    for (int g = 0; g < NG; g++) bb[g] = bias[g*256 + e];
    float hss = 0.f, css = 0.f;
    #pragma unroll
    for (int mi = 0; mi < 4; mi++){
      #pragma unroll
      for (int r = 0; r < 4; r++){
        int orow = mbase + wm + mi*16 + kg*4 + r;
        int node = sbase + orow;
        int chl = lidx[node];
        float sl = scH[chl >> 13];
        float cl = bfu2f(Cin[(size_t)chl*256 + e]) * scC[chl >> 13];
        float c2, h2;
        if constexpr (MODE == 1){
          float i_ = sigm(accL[mi][0][r]*sl + bb[0]);
          float f_ = sigm(accL[mi][1][r]*sl + bb[1]);
          float o_ = sigm(accL[mi][2][r]*sl + bb[2]);
          float u_ = tanh_(accL[mi][3][r]*sl + bb[3]);
          c2 = i_*u_ + f_*cl;
          h2 = o_*tanh_(c2);
        } else {
          int chr = ridx[node];
          float sr = scH[chr >> 13];
          float cr = bfu2f(Cin[(size_t)chr*256 + e]) * scC[chr >> 13];
          float g0 = accL[mi][0][r]*sl + accR[mi][0][r]*sr + bb[0];
          float g1 = accL[mi][1][r]*sl + accR[mi][1][r]*sr + bb[1];
          float g2 = accL[mi][2][r]*sl + accR[mi][2][r]*sr + bb[2];
          float g3 = accL[mi][3][r]*sl + accR[mi][3][r]*sr + bb[3];
          float g4 = accL[mi][4][r]*sl + accR[mi][4][r]*sr + bb[4];
          float i_ = sigm(g0);
          float fl = sigm(g1);
          float fr = sigm(g2);
          float o_ = sigm(g3);
          float u_ = tanh_(g4);
          c2 = i_*u_ + fl*cl + fr*cr;
          h2 = o_*tanh_(c2);
        }
        H[(size_t)node*256 + e] = f2bfu(h2);
        C[(size_t)node*256 + e] = f2bfu(c2);
        hss += h2*h2;
        css += c2*c2;
      }
    }
    #pragma unroll
    for (int o = 32; o; o >>= 1){ hss += __shfl_down(hss, o); css += __shfl_down(css, o); }
    if (lane == 0){ red[wave] = hss; red[8+wave] = css; }
    __syncthreads();
    if (tid == 0){
      float s = 0.f;
      #pragma unroll
      for (int w = 0; w < 8; w++) s += red[w];
      atomicAdd(&sumsq[step], s);
    }
    if (tid == 64){
      float s = 0.f;
      #pragma unroll
      for (int w = 0; w < 8; w++) s += red[8+w];
      atomicAdd(&sumsq[16 + step], s);
    }
  }
}

// ---------------------------------------------------------------- output: bf16->f32 with per-step H scale
__global__ __launch_bounds__(256) void out_kernel(
    const u16* __restrict__ H, const float* __restrict__ sumsq, float* __restrict__ out)
{
  size_t base = ((size_t)blockIdx.x*256 + threadIdx.x)*8;
  int n = (int)(base >> 8);
  float s = invs(sumsq[n >> 13]);
  const uint4 v = *reinterpret_cast<const uint4*>(H + base);
  float4 o0, o1;
  o0.x = bfu2f((u16)(v.x & 0xffff))*s; o0.y = bfu2f((u16)(v.x >> 16))*s;
  o0.z = bfu2f((u16)(v.y & 0xffff))*s; o0.w = bfu2f((u16)(v.y >> 16))*s;
  o1.x = bfu2f((u16)(v.z & 0xffff))*s; o1.y = bfu2f((u16)(v.z >> 16))*s;
  o1.z = bfu2f((u16)(v.w & 0xffff))*s; o1.w = bfu2f((u16)(v.w >> 16))*s;
  *reinterpret_cast<float4*>(out + base)     = o0;
  *reinterpret_cast<float4*>(out + base + 4) = o1;
}

// ---------------------------------------------------------------- host
extern "C" void kernel_launch(void* const* d_in, const int* in_sizes, int n_in,
                              void* d_out, int out_size, void* d_ws, size_t ws_size,
                              hipStream_t stream)
{
  const int*   tokens     = (const int*)d_in[0];
  const int*   lidx       = (const int*)d_in[1];
  const int*   ridx       = (const int*)d_in[2];
  const float* leaf_table = (const float*)d_in[6];
  const float* num_W1     = (const float*)d_in[7];
  const float* num_b1     = (const float*)d_in[8];
  const float* num_W2     = (const float*)d_in[9];
  const float* num_b2     = (const float*)d_in[10];
  const float* una_W      = (const float*)d_in[11];
  const float* una_b      = (const float*)d_in[12];
  const float* bin_W      = (const float*)d_in[13];
  const float* bin_b      = (const float*)d_in[14];

  // ws layout: H | wbu | wbb | wbn | h1 | sumsq
  char* ws = (char*)d_ws;
  size_t off = 0;
  u16* H   = (u16*)(ws + off); off += (size_t)N_TOTAL*256*2;
  u16* wbu = (u16*)(ws + off); off += (size_t)2048*256*2;
  u16* wbb = (u16*)(ws + off); off += (size_t)5120*256*2;
  u16* wbn = (u16*)(ws + off); off += (size_t)256*256*2;
  u16* h1  = (u16*)(ws + off); off += (size_t)G_STEP*256*2;
  float* sumsq = (float*)(ws + off); off += 32*4;

  u16* C = (u16*)d_out;  // dead before out_kernel overwrites

  setup_kernel<<<4001, 256, 0, stream>>>(tokens, leaf_table, num_W1, num_b1,
                                         una_W, bin_W, num_W2,
                                         wbu, wbb, wbn, h1, H, C, sumsq);
  gemm_fused<0><<<64, 512, 0, stream>>>(
      h1, nullptr, nullptr, wbn, num_b2, nullptr, sumsq, H, C, G_STEP, 1);

  const int sched[16] = {-1,-2,0,2,1,3,0,2,1,3,0,2,1,3,0,2};
  for (int d = 2; d < 16; d++){
    int op = sched[d];
    int sbase = d*G_STEP;
    if (op == 0 || op == 1){
      gemm_fused<1><<<256, 512, 0, stream>>>(
          H, lidx, nullptr, wbu + (size_t)op*1024*256,
          una_b + (size_t)op*4*256, C, sumsq, H, C, sbase, d);
    } else {
      int o2 = op - 2;
      gemm_fused<2><<<256, 512, 0, stream>>>(
          H, lidx, ridx, wbb + (size_t)o2*2*1280*256,
          bin_b + (size_t)o2*5*256, C, sumsq, H, C, sbase, d);
    }
  }
  out_kernel<<<(N_TOTAL*256)/(256*8), 256, 0, stream>>>(H, sumsq, (float*)d_out);
}